// Round 1
// baseline (15816.566 us; speedup 1.0000x reference)
//
#include <hip/hip_runtime.h>
#include <math.h>

#define N_NODES 50000
#define N_EDGES 500000
#define SD 128
#define VD 3
#define HID 64
#define DEPTH 4

__device__ __forceinline__ float silu_f(float x) {
    return x / (1.0f + __expf(-x));
}

// acc[0..63] += x.{x,y,z,w} * w[row][j], 4 consecutive rows of a (*,64) weight
__device__ __forceinline__ void fma4x64(float* acc, float4 x, const float* __restrict__ w) {
    #pragma unroll
    for (int j = 0; j < HID; j++) acc[j] += x.x * w[j];
    #pragma unroll
    for (int j = 0; j < HID; j++) acc[j] += x.y * w[HID + j];
    #pragma unroll
    for (int j = 0; j < HID; j++) acc[j] += x.z * w[2 * HID + j];
    #pragma unroll
    for (int j = 0; j < HID; j++) acc[j] += x.w * w[3 * HID + j];
}

// ---------------- setup kernels ----------------

__global__ void copy_kernel(const float* __restrict__ in, float* __restrict__ out, int n) {
    int i = blockIdx.x * blockDim.x + threadIdx.x;
    if (i < n) out[i] = in[i];
}

__global__ void prep_edges(const int* __restrict__ ei, const float* __restrict__ d,
                           float* __restrict__ C, float* __restrict__ cnt) {
    int e = blockIdx.x * blockDim.x + threadIdx.x;
    if (e >= N_EDGES) return;
    float de = d[e];
    float c = 0.5f * (cosf(3.14159265358979323846f * de * (1.0f / 5.0f)) + 1.0f);
    C[e] = (de < 5.0f) ? c : 0.0f;
    atomicAdd(&cnt[ei[e]], 1.0f);
}

__global__ void inv_cnt_kernel(float* __restrict__ cnt) {
    int i = blockIdx.x * blockDim.x + threadIdx.x;
    if (i < N_NODES) cnt[i] = 1.0f / fmaxf(cnt[i], 1.0f);
}

// W: (DEPTH, rows, cols) -> WT: (DEPTH, cols, rows)
__global__ void transpose_kernel(const float* __restrict__ W, float* __restrict__ WT,
                                 int rows, int cols) {
    int idx = blockIdx.x * blockDim.x + threadIdx.x;
    int total = DEPTH * rows * cols;
    if (idx >= total) return;
    int l = idx / (rows * cols);
    int rem = idx - l * rows * cols;
    int rr = rem / cols;
    int cc = rem - rr * cols;
    WT[((size_t)l * cols + cc) * rows + rr] = W[idx];
}

// ---------------- edge kernel ----------------
// One thread per edge. Weights are wave-uniform -> scalar loads.
// h1 round-trips through LDS so both matmul stages keep accumulator arrays
// statically indexed (no VGPR-array dynamic indexing -> no scratch spill).
__global__ __launch_bounds__(64) void edge_kernel(
    const float* __restrict__ s, const float* __restrict__ v,
    const int* __restrict__ ei, const float* __restrict__ d,
    const float* __restrict__ r, const float* __restrict__ C,
    const float* __restrict__ W1, const float* __restrict__ b1,
    const float* __restrict__ W2, const float* __restrict__ b2,
    const float* __restrict__ W3T, const float* __restrict__ b3,
    float* __restrict__ s_agg, float* __restrict__ v_agg)
{
    __shared__ float h1s[64 * 65];   // stride 65: 2-way bank aliasing (free)
    int e = blockIdx.x * 64 + threadIdx.x;
    bool active = (e < N_EDGES);
    int ee = active ? e : 0;
    int dst = ei[ee];
    int src = ei[N_EDGES + ee];
    float de = d[ee];
    float Ce = C[ee];

    // ---- h1 = silu([s_dst, s_src, d] @ W1 + b1) ----
    float acc[HID];
    #pragma unroll
    for (int j = 0; j < HID; j++) acc[j] = b1[j] + de * W1[256 * HID + j];

    const float4* a4 = reinterpret_cast<const float4*>(s + (size_t)dst * SD);
    for (int i4 = 0; i4 < SD / 4; i4++) {
        fma4x64(acc, a4[i4], W1 + (size_t)i4 * 4 * HID);
    }
    const float4* b4 = reinterpret_cast<const float4*>(s + (size_t)src * SD);
    for (int i4 = 0; i4 < SD / 4; i4++) {
        fma4x64(acc, b4[i4], W1 + ((size_t)SD + i4 * 4) * HID);
    }
    #pragma unroll
    for (int j = 0; j < HID; j++) h1s[threadIdx.x * 65 + j] = silu_f(acc[j]);
    // thread-private LDS rows: no barrier needed

    // ---- h2 = silu(h1 @ W2 + b2) ----
    float h2[HID];
    #pragma unroll
    for (int j = 0; j < HID; j++) h2[j] = b2[j];
    for (int k = 0; k < HID; k++) {
        float hk = h1s[threadIdx.x * 65 + k];
        const float* w = W2 + (size_t)k * HID;
        #pragma unroll
        for (int j = 0; j < HID; j++) h2[j] += hk * w[j];
    }
    #pragma unroll
    for (int j = 0; j < HID; j++) h2[j] = silu_f(h2[j]);

    if (!active) return;

    // ---- m = h2 @ W3 + b3; scatter ms*C and vm ----
    float* sg = s_agg + (size_t)dst * SD;
    for (int j = 0; j < SD; j++) {
        const float* w = W3T + (size_t)j * HID;
        float mj = b3[j];
        #pragma unroll
        for (int k = 0; k < HID; k++) mj += h2[k] * w[k];
        atomicAdd(&sg[j], mj * Ce);
    }
    float g[2 * VD];
    #pragma unroll
    for (int t = 0; t < 2 * VD; t++) {
        const float* w = W3T + ((size_t)SD + t) * HID;
        float mj = b3[SD + t];
        #pragma unroll
        for (int k = 0; k < HID; k++) mj += h2[k] * w[k];
        g[t] = mj;
    }
    float rv0 = r[3 * (size_t)e], rv1 = r[3 * (size_t)e + 1], rv2 = r[3 * (size_t)e + 2];
    const float* vs = v + (size_t)src * (VD * 3);
    float* vg = v_agg + (size_t)dst * (VD * 3);
    #pragma unroll
    for (int vi = 0; vi < VD; vi++) {
        float gv = g[vi], gr = g[VD + vi];
        atomicAdd(&vg[vi * 3 + 0], (vs[vi * 3 + 0] * gv + rv0 * gr) * Ce);
        atomicAdd(&vg[vi * 3 + 1], (vs[vi * 3 + 1] * gv + rv1 * gr) * Ce);
        atomicAdd(&vg[vi * 3 + 2], (vs[vi * 3 + 2] * gv + rv2 * gr) * Ce);
    }
}

// ---------------- node kernel ----------------
__global__ __launch_bounds__(64) void node_kernel(
    float* __restrict__ s, float* __restrict__ v,
    const float* __restrict__ s_agg, const float* __restrict__ v_agg,
    const float* __restrict__ inv_cnt,
    const float* __restrict__ Wn1, const float* __restrict__ bn1,
    const float* __restrict__ Wn2T, const float* __restrict__ bn2)
{
    int n = blockIdx.x * 64 + threadIdx.x;
    if (n >= N_NODES) return;

    float u[HID];
    #pragma unroll
    for (int j = 0; j < HID; j++) u[j] = bn1[j];

    const float4* s4 = reinterpret_cast<const float4*>(s + (size_t)n * SD);
    for (int i4 = 0; i4 < SD / 4; i4++) {
        fma4x64(u, s4[i4], Wn1 + (size_t)i4 * 4 * HID);
    }
    const float4* a4 = reinterpret_cast<const float4*>(s_agg + (size_t)n * SD);
    for (int i4 = 0; i4 < SD / 4; i4++) {
        fma4x64(u, a4[i4], Wn1 + ((size_t)SD + i4 * 4) * HID);
    }
    #pragma unroll
    for (int j = 0; j < HID; j++) u[j] = silu_f(u[j]);

    float* srow = s + (size_t)n * SD;
    for (int j = 0; j < SD; j++) {
        const float* w = Wn2T + (size_t)j * HID;
        float acc = bn2[j];
        #pragma unroll
        for (int k = 0; k < HID; k++) acc += u[k] * w[k];
        srow[j] += acc;
    }
    float ic = inv_cnt[n];
    #pragma unroll
    for (int t = 0; t < VD * 3; t++)
        v[(size_t)n * (VD * 3) + t] += v_agg[(size_t)n * (VD * 3) + t] * ic;
}

// ---------------- launch ----------------
extern "C" void kernel_launch(void* const* d_in, const int* in_sizes, int n_in,
                              void* d_out, int out_size, void* d_ws, size_t ws_size,
                              hipStream_t stream)
{
    (void)in_sizes; (void)n_in; (void)out_size; (void)ws_size;
    const float* s_in = (const float*)d_in[0];
    const float* v_in = (const float*)d_in[1];
    const int*   ei   = (const int*)d_in[2];
    const float* d_e  = (const float*)d_in[3];
    const float* r_e  = (const float*)d_in[4];
    const float* W1   = (const float*)d_in[5];
    const float* b1   = (const float*)d_in[6];
    const float* W2   = (const float*)d_in[7];
    const float* b2   = (const float*)d_in[8];
    const float* W3   = (const float*)d_in[9];
    const float* b3   = (const float*)d_in[10];
    const float* Wn1  = (const float*)d_in[11];
    const float* bn1  = (const float*)d_in[12];
    const float* Wn2  = (const float*)d_in[13];
    const float* bn2  = (const float*)d_in[14];

    float* s = (float*)d_out;                 // N*SD, updated in place
    float* v = s + (size_t)N_NODES * SD;      // N*VD*3

    float* ws     = (float*)d_ws;
    float* s_agg  = ws;                                      // N*SD
    float* v_agg  = s_agg + (size_t)N_NODES * SD;            // N*9 (contiguous with s_agg)
    float* cntinv = v_agg + (size_t)N_NODES * VD * 3;        // N
    float* Cbuf   = cntinv + N_NODES;                        // E
    float* W3T    = Cbuf + N_EDGES;                          // DEPTH*134*64
    float* Wn2T   = W3T + (size_t)DEPTH * (SD + 2 * VD) * HID; // DEPTH*128*64

    hipMemsetAsync(cntinv, 0, N_NODES * sizeof(float), stream);
    copy_kernel<<<(N_NODES * SD + 255) / 256, 256, 0, stream>>>(s_in, s, N_NODES * SD);
    copy_kernel<<<(N_NODES * VD * 3 + 255) / 256, 256, 0, stream>>>(v_in, v, N_NODES * VD * 3);
    prep_edges<<<(N_EDGES + 255) / 256, 256, 0, stream>>>(ei, d_e, Cbuf, cntinv);
    inv_cnt_kernel<<<(N_NODES + 255) / 256, 256, 0, stream>>>(cntinv);
    transpose_kernel<<<(DEPTH * HID * (SD + 2 * VD) + 255) / 256, 256, 0, stream>>>(
        W3, W3T, HID, SD + 2 * VD);
    transpose_kernel<<<(DEPTH * HID * SD + 255) / 256, 256, 0, stream>>>(
        Wn2, Wn2T, HID, SD);

    for (int l = 0; l < DEPTH; l++) {
        // zero s_agg + v_agg (contiguous)
        hipMemsetAsync(s_agg, 0,
                       ((size_t)N_NODES * SD + (size_t)N_NODES * VD * 3) * sizeof(float),
                       stream);
        edge_kernel<<<(N_EDGES + 63) / 64, 64, 0, stream>>>(
            s, v, ei, d_e, r_e, Cbuf,
            W1 + (size_t)l * (2 * SD + 1) * HID, b1 + (size_t)l * HID,
            W2 + (size_t)l * HID * HID,          b2 + (size_t)l * HID,
            W3T + (size_t)l * (SD + 2 * VD) * HID, b3 + (size_t)l * (SD + 2 * VD),
            s_agg, v_agg);
        node_kernel<<<(N_NODES + 63) / 64, 64, 0, stream>>>(
            s, v, s_agg, v_agg, cntinv,
            Wn1 + (size_t)l * 2 * SD * HID, bn1 + (size_t)l * HID,
            Wn2T + (size_t)l * SD * HID,    bn2 + (size_t)l * SD);
    }
}

// Round 2
// 4445.541 us; speedup vs baseline: 3.5578x; 3.5578x over previous
//
#include <hip/hip_runtime.h>
#include <hip/hip_bf16.h>
#include <math.h>

#define N_NODES 50000
#define N_EDGES 500000
#define SD 128
#define VD 3
#define HID 64
#define DEPTH 4

__device__ __forceinline__ float silu_f(float x) {
    return x / (1.0f + __expf(-x));
}

__device__ __forceinline__ unsigned short f2bf(float x) {
    __hip_bfloat16 h = __float2bfloat16(x);
    return *reinterpret_cast<unsigned short*>(&h);
}

__device__ __forceinline__ float bf2f(unsigned short u) {
    unsigned int t = ((unsigned int)u) << 16;
    union { unsigned int i; float f; } c; c.i = t;
    return c.f;
}

// acc[0..63] += x.{x,y,z,w} * w[row][j], 4 consecutive rows of a (*,64) weight
__device__ __forceinline__ void fma4x64(float* acc, float4 x, const float* __restrict__ w) {
    #pragma unroll
    for (int j = 0; j < HID; j++) acc[j] += x.x * w[j];
    #pragma unroll
    for (int j = 0; j < HID; j++) acc[j] += x.y * w[HID + j];
    #pragma unroll
    for (int j = 0; j < HID; j++) acc[j] += x.z * w[2 * HID + j];
    #pragma unroll
    for (int j = 0; j < HID; j++) acc[j] += x.w * w[3 * HID + j];
}

// ---------------- setup kernels ----------------

__global__ void copy_kernel(const float* __restrict__ in, float* __restrict__ out, int n) {
    int i = blockIdx.x * blockDim.x + threadIdx.x;
    if (i < n) out[i] = in[i];
}

__global__ void prep_edges(const int* __restrict__ ei, const float* __restrict__ d,
                           float* __restrict__ C, int* __restrict__ cnti) {
    int e = blockIdx.x * blockDim.x + threadIdx.x;
    if (e >= N_EDGES) return;
    float de = d[e];
    float c = 0.5f * (cosf(3.14159265358979323846f * de * (1.0f / 5.0f)) + 1.0f);
    C[e] = (de < 5.0f) ? c : 0.0f;
    atomicAdd(&cnti[ei[e]], 1);
}

__global__ void inv_cnt_kernel(const int* __restrict__ cnti, float* __restrict__ inv_cnt) {
    int i = blockIdx.x * blockDim.x + threadIdx.x;
    if (i < N_NODES) inv_cnt[i] = 1.0f / fmaxf((float)cnti[i], 1.0f);
}

// single-block exclusive scan of cnti[N] -> offs[N+1]
__global__ __launch_bounds__(1024) void scan_kernel(const int* __restrict__ cnti,
                                                    int* __restrict__ offs) {
    __shared__ int sh[1024];
    __shared__ int carry_s;
    int tid = threadIdx.x;
    if (tid == 0) carry_s = 0;
    __syncthreads();
    for (int base = 0; base < N_NODES; base += 1024) {
        int idx = base + tid;
        int x = (idx < N_NODES) ? cnti[idx] : 0;
        sh[tid] = x;
        __syncthreads();
        for (int off = 1; off < 1024; off <<= 1) {
            int y = (tid >= off) ? sh[tid - off] : 0;
            __syncthreads();
            sh[tid] += y;
            __syncthreads();
        }
        int excl = ((tid > 0) ? sh[tid - 1] : 0) + carry_s;
        if (idx < N_NODES) offs[idx] = excl;
        __syncthreads();
        if (tid == 0) carry_s += sh[1023];
        __syncthreads();
    }
    if (tid == 0) offs[N_NODES] = carry_s;
}

__global__ void build_perm(const int* __restrict__ ei, const int* __restrict__ offs,
                           int* __restrict__ cursor, int* __restrict__ eids) {
    int e = blockIdx.x * blockDim.x + threadIdx.x;
    if (e >= N_EDGES) return;
    int dst = ei[e];
    int p = offs[dst] + atomicAdd(&cursor[dst], 1);
    eids[p] = e;
}

// W: (DEPTH, rows, cols) -> WT: (DEPTH, cols, rows)
__global__ void transpose_kernel(const float* __restrict__ W, float* __restrict__ WT,
                                 int rows, int cols) {
    int idx = blockIdx.x * blockDim.x + threadIdx.x;
    int total = DEPTH * rows * cols;
    if (idx >= total) return;
    int l = idx / (rows * cols);
    int rem = idx - l * rows * cols;
    int rr = rem / cols;
    int cc = rem - rr * cols;
    WT[((size_t)l * cols + cc) * rows + rr] = W[idx];
}

// ---------------- edge kernel ----------------
// One thread per edge; weights wave-uniform (scalar loads). Messages are
// materialized as bf16 (no atomics): smsg[e][0..127] = ms*C, vmsg[e][0..8] = vm*C.
__global__ __launch_bounds__(64) void edge_kernel(
    const float* __restrict__ s, const float* __restrict__ v,
    const int* __restrict__ ei, const float* __restrict__ d,
    const float* __restrict__ r, const float* __restrict__ C,
    const float* __restrict__ W1, const float* __restrict__ b1,
    const float* __restrict__ W2, const float* __restrict__ b2,
    const float* __restrict__ W3T, const float* __restrict__ b3,
    unsigned short* __restrict__ smsg, unsigned short* __restrict__ vmsg)
{
    __shared__ float h1s[64 * 65];   // stride 65: 2-way bank aliasing (free)
    int e = blockIdx.x * 64 + threadIdx.x;
    bool active = (e < N_EDGES);
    int ee = active ? e : 0;
    int dst = ei[ee];
    int src = ei[N_EDGES + ee];
    float de = d[ee];
    float Ce = C[ee];

    // ---- h1 = silu([s_dst, s_src, d] @ W1 + b1) ----
    float acc[HID];
    #pragma unroll
    for (int j = 0; j < HID; j++) acc[j] = b1[j] + de * W1[256 * HID + j];

    const float4* a4 = reinterpret_cast<const float4*>(s + (size_t)dst * SD);
    for (int i4 = 0; i4 < SD / 4; i4++) {
        fma4x64(acc, a4[i4], W1 + (size_t)i4 * 4 * HID);
    }
    const float4* b4 = reinterpret_cast<const float4*>(s + (size_t)src * SD);
    for (int i4 = 0; i4 < SD / 4; i4++) {
        fma4x64(acc, b4[i4], W1 + ((size_t)SD + i4 * 4) * HID);
    }
    #pragma unroll
    for (int j = 0; j < HID; j++) h1s[threadIdx.x * 65 + j] = silu_f(acc[j]);
    // thread-private LDS rows: no barrier needed

    // ---- h2 = silu(h1 @ W2 + b2) ----
    float h2[HID];
    #pragma unroll
    for (int j = 0; j < HID; j++) h2[j] = b2[j];
    for (int k = 0; k < HID; k++) {
        float hk = h1s[threadIdx.x * 65 + k];
        const float* w = W2 + (size_t)k * HID;
        #pragma unroll
        for (int j = 0; j < HID; j++) h2[j] += hk * w[j];
    }
    #pragma unroll
    for (int j = 0; j < HID; j++) h2[j] = silu_f(h2[j]);

    if (!active) return;

    // ---- m = h2 @ W3 + b3; store bf16 messages ----
    ushort4* srow = reinterpret_cast<ushort4*>(smsg + (size_t)e * SD);
    for (int j = 0; j < SD; j += 4) {
        float m[4];
        #pragma unroll
        for (int t = 0; t < 4; t++) {
            const float* w = W3T + (size_t)(j + t) * HID;
            float mj = b3[j + t];
            #pragma unroll
            for (int k = 0; k < HID; k++) mj += h2[k] * w[k];
            m[t] = mj * Ce;
        }
        ushort4 u;
        u.x = f2bf(m[0]); u.y = f2bf(m[1]); u.z = f2bf(m[2]); u.w = f2bf(m[3]);
        srow[j / 4] = u;
    }

    float g[2 * VD];
    #pragma unroll
    for (int t = 0; t < 2 * VD; t++) {
        const float* w = W3T + ((size_t)SD + t) * HID;
        float mj = b3[SD + t];
        #pragma unroll
        for (int k = 0; k < HID; k++) mj += h2[k] * w[k];
        g[t] = mj;
    }
    float rv[3] = { r[3 * (size_t)e], r[3 * (size_t)e + 1], r[3 * (size_t)e + 2] };
    const float* vs = v + (size_t)src * (VD * 3);
    float vm[12];
    #pragma unroll
    for (int vi = 0; vi < VD; vi++) {
        float gv = g[vi], gr = g[VD + vi];
        #pragma unroll
        for (int c = 0; c < 3; c++)
            vm[vi * 3 + c] = (vs[vi * 3 + c] * gv + rv[c] * gr) * Ce;
    }
    vm[9] = 0.0f; vm[10] = 0.0f; vm[11] = 0.0f;
    ushort4* vrow = reinterpret_cast<ushort4*>(vmsg + (size_t)e * 12);
    #pragma unroll
    for (int q = 0; q < 3; q++) {
        ushort4 u;
        u.x = f2bf(vm[q * 4 + 0]); u.y = f2bf(vm[q * 4 + 1]);
        u.z = f2bf(vm[q * 4 + 2]); u.w = f2bf(vm[q * 4 + 3]);
        vrow[q] = u;
    }
}

// ---------------- aggregation kernel ----------------
// One wave per node: gather bf16 message rows via CSR, sum in fp32.
__global__ __launch_bounds__(256) void agg_kernel(
    const unsigned short* __restrict__ smsg, const unsigned short* __restrict__ vmsg,
    const int* __restrict__ offs, const int* __restrict__ eids,
    float* __restrict__ s_agg, float* __restrict__ v_agg)
{
    int wave = blockIdx.x * 4 + (threadIdx.x >> 6);
    int lane = threadIdx.x & 63;
    if (wave >= N_NODES) return;
    int beg = offs[wave], end = offs[wave + 1];
    float a0 = 0.0f, a1 = 0.0f, va = 0.0f;
    const ushort2* sm2 = reinterpret_cast<const ushort2*>(smsg);
    for (int i = beg; i < end; i++) {
        int e = eids[i];
        ushort2 mm = sm2[(size_t)e * 64 + lane];
        a0 += bf2f(mm.x);
        a1 += bf2f(mm.y);
        if (lane < 9) va += bf2f(vmsg[(size_t)e * 12 + lane]);
    }
    s_agg[(size_t)wave * SD + lane * 2]     = a0;
    s_agg[(size_t)wave * SD + lane * 2 + 1] = a1;
    if (lane < 9) v_agg[(size_t)wave * 9 + lane] = va;
}

// ---------------- node kernel ----------------
__global__ __launch_bounds__(256) void node_kernel(
    float* __restrict__ s, float* __restrict__ v,
    const float* __restrict__ s_agg, const float* __restrict__ v_agg,
    const float* __restrict__ inv_cnt,
    const float* __restrict__ Wn1, const float* __restrict__ bn1,
    const float* __restrict__ Wn2T, const float* __restrict__ bn2)
{
    int n = blockIdx.x * 256 + threadIdx.x;
    if (n >= N_NODES) return;

    float u[HID];
    #pragma unroll
    for (int j = 0; j < HID; j++) u[j] = bn1[j];

    const float4* s4 = reinterpret_cast<const float4*>(s + (size_t)n * SD);
    for (int i4 = 0; i4 < SD / 4; i4++) {
        fma4x64(u, s4[i4], Wn1 + (size_t)i4 * 4 * HID);
    }
    const float4* a4 = reinterpret_cast<const float4*>(s_agg + (size_t)n * SD);
    for (int i4 = 0; i4 < SD / 4; i4++) {
        fma4x64(u, a4[i4], Wn1 + ((size_t)SD + i4 * 4) * HID);
    }
    #pragma unroll
    for (int j = 0; j < HID; j++) u[j] = silu_f(u[j]);

    float* srow = s + (size_t)n * SD;
    for (int j = 0; j < SD; j++) {
        const float* w = Wn2T + (size_t)j * HID;
        float acc = bn2[j];
        #pragma unroll
        for (int k = 0; k < HID; k++) acc += u[k] * w[k];
        srow[j] += acc;
    }
    float ic = inv_cnt[n];
    #pragma unroll
    for (int t = 0; t < VD * 3; t++)
        v[(size_t)n * (VD * 3) + t] += v_agg[(size_t)n * 9 + t] * ic;
}

// ---------------- launch ----------------
extern "C" void kernel_launch(void* const* d_in, const int* in_sizes, int n_in,
                              void* d_out, int out_size, void* d_ws, size_t ws_size,
                              hipStream_t stream)
{
    (void)in_sizes; (void)n_in; (void)out_size; (void)ws_size;
    const float* s_in = (const float*)d_in[0];
    const float* v_in = (const float*)d_in[1];
    const int*   ei   = (const int*)d_in[2];
    const float* d_e  = (const float*)d_in[3];
    const float* r_e  = (const float*)d_in[4];
    const float* W1   = (const float*)d_in[5];
    const float* b1   = (const float*)d_in[6];
    const float* W2   = (const float*)d_in[7];
    const float* b2   = (const float*)d_in[8];
    const float* W3   = (const float*)d_in[9];
    const float* b3   = (const float*)d_in[10];
    const float* Wn1  = (const float*)d_in[11];
    const float* bn1  = (const float*)d_in[12];
    const float* Wn2  = (const float*)d_in[13];
    const float* bn2  = (const float*)d_in[14];

    float* s = (float*)d_out;                 // N*SD, updated in place
    float* v = s + (size_t)N_NODES * SD;      // N*VD*3

    // ---- workspace layout (floats unless noted) ----
    float* ws      = (float*)d_ws;
    float* s_agg   = ws;                                        // N*SD
    float* v_agg   = s_agg + (size_t)N_NODES * SD;              // N*9
    float* cntinv  = v_agg + (size_t)N_NODES * 9;               // N
    float* Cbuf    = cntinv + N_NODES;                          // E
    float* W3T     = Cbuf + N_EDGES;                            // DEPTH*134*64
    float* Wn2T    = W3T + (size_t)DEPTH * (SD + 2 * VD) * HID; // DEPTH*128*64
    int*   cnti    = (int*)(Wn2T + (size_t)DEPTH * SD * HID);   // N
    int*   offs    = cnti + N_NODES;                            // N+1
    int*   cursor  = offs + N_NODES + 1;                        // N
    int*   eids    = cursor + N_NODES;                          // E
    unsigned short* smsg = (unsigned short*)(eids + N_EDGES);   // E*128 bf16
    unsigned short* vmsg = smsg + (size_t)N_EDGES * SD;         // E*12 bf16

    // zero cnti + cursor
    hipMemsetAsync(cnti, 0, sizeof(int) * (size_t)N_NODES, stream);
    hipMemsetAsync(cursor, 0, sizeof(int) * (size_t)N_NODES, stream);

    copy_kernel<<<(N_NODES * SD + 255) / 256, 256, 0, stream>>>(s_in, s, N_NODES * SD);
    copy_kernel<<<(N_NODES * VD * 3 + 255) / 256, 256, 0, stream>>>(v_in, v, N_NODES * VD * 3);
    prep_edges<<<(N_EDGES + 255) / 256, 256, 0, stream>>>(ei, d_e, Cbuf, cnti);
    inv_cnt_kernel<<<(N_NODES + 255) / 256, 256, 0, stream>>>(cnti, cntinv);
    scan_kernel<<<1, 1024, 0, stream>>>(cnti, offs);
    build_perm<<<(N_EDGES + 255) / 256, 256, 0, stream>>>(ei, offs, cursor, eids);
    transpose_kernel<<<(DEPTH * HID * (SD + 2 * VD) + 255) / 256, 256, 0, stream>>>(
        W3, W3T, HID, SD + 2 * VD);
    transpose_kernel<<<(DEPTH * HID * SD + 255) / 256, 256, 0, stream>>>(
        Wn2, Wn2T, HID, SD);

    for (int l = 0; l < DEPTH; l++) {
        edge_kernel<<<(N_EDGES + 63) / 64, 64, 0, stream>>>(
            s, v, ei, d_e, r_e, Cbuf,
            W1 + (size_t)l * (2 * SD + 1) * HID, b1 + (size_t)l * HID,
            W2 + (size_t)l * HID * HID,          b2 + (size_t)l * HID,
            W3T + (size_t)l * (SD + 2 * VD) * HID, b3 + (size_t)l * (SD + 2 * VD),
            smsg, vmsg);
        agg_kernel<<<(N_NODES + 3) / 4, 256, 0, stream>>>(
            smsg, vmsg, offs, eids, s_agg, v_agg);
        node_kernel<<<(N_NODES + 255) / 256, 256, 0, stream>>>(
            s, v, s_agg, v_agg, cntinv,
            Wn1 + (size_t)l * 2 * SD * HID, bn1 + (size_t)l * HID,
            Wn2T + (size_t)l * SD * HID,    bn2 + (size_t)l * SD);
    }
}

// Round 3
// 1882.211 us; speedup vs baseline: 8.4032x; 2.3619x over previous
//
#include <hip/hip_runtime.h>
#include <hip/hip_bf16.h>
#include <math.h>

#define N_NODES 50000
#define N_EDGES 500000
#define SD 128
#define VD 3
#define HID 64
#define DEPTH 4

// packed bf16 weight block per layer: W1T(64x264) + W2T(64x72) + W3T(144x72)
#define W1T_SH (64 * 264)
#define W2T_SH (64 * 72)
#define W3T_SH (144 * 72)
#define WPK_SH (W1T_SH + W2T_SH + W3T_SH)   // 31872 shorts per layer

typedef __attribute__((ext_vector_type(8))) short short8;
typedef __attribute__((ext_vector_type(4))) float f32x4;

__device__ __forceinline__ float silu_f(float x) {
    return x / (1.0f + __expf(-x));
}

__device__ __forceinline__ unsigned short f2bf(float x) {
    __hip_bfloat16 h = __float2bfloat16(x);
    return *reinterpret_cast<unsigned short*>(&h);
}

__device__ __forceinline__ float bf2f(unsigned short u) {
    union { unsigned int i; float f; } c; c.i = ((unsigned int)u) << 16;
    return c.f;
}

// acc[0..63] += x.{x,y,z,w} * w[row][j]
__device__ __forceinline__ void fma4x64(float* acc, float4 x, const float* __restrict__ w) {
    #pragma unroll
    for (int j = 0; j < HID; j++) acc[j] += x.x * w[j];
    #pragma unroll
    for (int j = 0; j < HID; j++) acc[j] += x.y * w[HID + j];
    #pragma unroll
    for (int j = 0; j < HID; j++) acc[j] += x.z * w[2 * HID + j];
    #pragma unroll
    for (int j = 0; j < HID; j++) acc[j] += x.w * w[3 * HID + j];
}

// ---------------- setup kernels ----------------

__global__ void cast_s_kernel(const float* __restrict__ in, float* __restrict__ out,
                              unsigned short* __restrict__ out_bf, int n) {
    int i = blockIdx.x * blockDim.x + threadIdx.x;
    if (i < n) { float x = in[i]; out[i] = x; out_bf[i] = f2bf(x); }
}

__global__ void copy_kernel(const float* __restrict__ in, float* __restrict__ out, int n) {
    int i = blockIdx.x * blockDim.x + threadIdx.x;
    if (i < n) out[i] = in[i];
}

__global__ void prep_edges(const int* __restrict__ ei, const float* __restrict__ d,
                           float* __restrict__ C, int* __restrict__ cnti) {
    int e = blockIdx.x * blockDim.x + threadIdx.x;
    if (e >= N_EDGES) return;
    float de = d[e];
    float c = 0.5f * (cosf(3.14159265358979323846f * de * (1.0f / 5.0f)) + 1.0f);
    C[e] = (de < 5.0f) ? c : 0.0f;
    atomicAdd(&cnti[ei[e]], 1);
}

__global__ void inv_cnt_kernel(const int* __restrict__ cnti, float* __restrict__ inv_cnt) {
    int i = blockIdx.x * blockDim.x + threadIdx.x;
    if (i < N_NODES) inv_cnt[i] = 1.0f / fmaxf((float)cnti[i], 1.0f);
}

// multi-block scan: phase 1 — per-block exclusive scan + block sums
__global__ __launch_bounds__(1024) void scan_block(const int* __restrict__ cnti,
                                                   int* __restrict__ offs,
                                                   int* __restrict__ bsum) {
    __shared__ int sh[1024];
    int tid = threadIdx.x;
    int idx = blockIdx.x * 1024 + tid;
    int x = (idx < N_NODES) ? cnti[idx] : 0;
    sh[tid] = x;
    __syncthreads();
    for (int off = 1; off < 1024; off <<= 1) {
        int y = (tid >= off) ? sh[tid - off] : 0;
        __syncthreads();
        sh[tid] += y;
        __syncthreads();
    }
    if (idx < N_NODES) offs[idx] = sh[tid] - x;   // exclusive, block-local
    if (tid == 1023) bsum[blockIdx.x] = sh[1023];
}

// phase 2 — scan the (49) block sums serially, write grand total to offs[N]
__global__ void scan_partials(int* __restrict__ bsum, int nb, int* __restrict__ offs_total) {
    if (threadIdx.x == 0 && blockIdx.x == 0) {
        int acc = 0;
        for (int i = 0; i < nb; i++) { int t = bsum[i]; bsum[i] = acc; acc += t; }
        offs_total[0] = acc;
    }
}

// phase 3 — add block offsets
__global__ __launch_bounds__(1024) void scan_apply(int* __restrict__ offs,
                                                   const int* __restrict__ bsum) {
    int idx = blockIdx.x * 1024 + threadIdx.x;
    if (idx < N_NODES) offs[idx] += bsum[blockIdx.x];
}

__global__ void build_perm(const int* __restrict__ ei, const int* __restrict__ offs,
                           int* __restrict__ cursor, int* __restrict__ eids) {
    int e = blockIdx.x * blockDim.x + threadIdx.x;
    if (e >= N_EDGES) return;
    int dst = ei[e];
    int p = offs[dst] + atomicAdd(&cursor[dst], 1);
    eids[p] = e;
}

// W: (DEPTH, rows, cols) fp32 -> WT: (DEPTH, cols, rows) fp32
__global__ void transpose_kernel(const float* __restrict__ W, float* __restrict__ WT,
                                 int rows, int cols) {
    int idx = blockIdx.x * blockDim.x + threadIdx.x;
    int total = DEPTH * rows * cols;
    if (idx >= total) return;
    int l = idx / (rows * cols);
    int rem = idx - l * rows * cols;
    int rr = rem / cols;
    int cc = rem - rr * cols;
    WT[((size_t)l * cols + cc) * rows + rr] = W[idx];
}

// pack transposed bf16 weights for the edge MLP:
//   W1T[n][k] (64x264, k<257 valid), W2T[n][k] (64x72, k<64), W3T[n][k] (144x72, n<134,k<64)
__global__ void prep_weights(const float* __restrict__ W1, const float* __restrict__ W2,
                             const float* __restrict__ W3, unsigned short* __restrict__ Wpk) {
    int idx = blockIdx.x * blockDim.x + threadIdx.x;
    if (idx >= DEPTH * WPK_SH) return;
    int l = idx / WPK_SH;
    int j = idx - l * WPK_SH;
    float val = 0.0f;
    if (j < W1T_SH) {
        int n = j / 264, k = j - n * 264;
        if (k < 257) val = W1[((size_t)l * 257 + k) * 64 + n];
    } else if (j < W1T_SH + W2T_SH) {
        int jj = j - W1T_SH;
        int n = jj / 72, k = jj - n * 72;
        if (k < 64) val = W2[((size_t)l * 64 + k) * 64 + n];
    } else {
        int jj = j - W1T_SH - W2T_SH;
        int n = jj / 72, k = jj - n * 72;
        if (n < 134 && k < 64) val = W3[((size_t)l * 64 + k) * 134 + n];
    }
    Wpk[idx] = f2bf(val);
}

// ---------------- MFMA edge kernel ----------------
// block = 256 threads = 4 waves; wave handles 16 edges through the 3-layer MLP.
// A-frag: lane holds A[m=lane&15][k=quad*8+j]; B-frag: B[k=quad*8+j][n=lane&15]
// from transposed weights; C/D: col=lane&15, row=quad*4+reg.
__global__ __launch_bounds__(256) void edge_mfma(
    const unsigned short* __restrict__ s_bf, const float* __restrict__ v,
    const int* __restrict__ ei, const float* __restrict__ d_e,
    const float* __restrict__ Cbuf, const float* __restrict__ r_e,
    const unsigned short* __restrict__ Wpk_l,   // this layer's packed bf16 weights
    const float* __restrict__ W1r,              // fp32 W1 row 256 (the d feature)
    const float* __restrict__ b1, const float* __restrict__ b2,
    const float* __restrict__ b3,
    unsigned short* __restrict__ smsg, unsigned short* __restrict__ vmsg)
{
    __shared__ __align__(16) unsigned short w1s[W1T_SH];   // 33792 B
    __shared__ __align__(16) unsigned short w2s[W2T_SH];   //  9216 B
    __shared__ __align__(16) unsigned short Hb[4][16 * 72]; //  9216 B (H1 then H2)
    __shared__ int dstl[64], srcl[64];
    __shared__ float dcl[64], cel[64];
    __shared__ float gb[4][16][6];

    const int tid  = threadIdx.x;
    const int wl   = tid >> 6;
    const int lane = tid & 63;
    const int lo   = lane & 15;
    const int q    = lane >> 4;
    const int wb   = wl * 16;
    const long eb  = (long)blockIdx.x * 64 + wb;   // wave's first edge

    // stage W1T + W2T into LDS (16B vector copies)
    {
        const short8* g  = reinterpret_cast<const short8*>(Wpk_l);
        short8* l1 = reinterpret_cast<short8*>(w1s);
        short8* l2 = reinterpret_cast<short8*>(w2s);
        for (int i = tid; i < W1T_SH / 8; i += 256) l1[i] = g[i];
        for (int i = tid; i < W2T_SH / 8; i += 256) l2[i] = g[W1T_SH / 8 + i];
    }
    if (lane < 16) {
        long e = eb + lane; if (e > N_EDGES - 1) e = N_EDGES - 1;
        dstl[wb + lane] = ei[e];
        srcl[wb + lane] = ei[N_EDGES + e];
        dcl[wb + lane]  = d_e[e];
        cel[wb + lane]  = Cbuf[e];
    }
    __syncthreads();

    // ---- L1: [s_dst | s_src | d] @ W1 + b1, K=256 via MFMA + d on VALU ----
    f32x4 acc1[4];
    #pragma unroll
    for (int t = 0; t < 4; t++) {
        int n = t * 16 + lo;
        float bb = b1[n], wr = W1r[n];
        #pragma unroll
        for (int rr = 0; rr < 4; rr++)
            acc1[t][rr] = bb + dcl[wb + 4 * q + rr] * wr;
    }
    const unsigned short* rowd = s_bf + (size_t)dstl[wb + lo] * SD;
    const unsigned short* rows = s_bf + (size_t)srcl[wb + lo] * SD;
    #pragma unroll
    for (int ks = 0; ks < 4; ks++) {
        short8 a = *reinterpret_cast<const short8*>(rowd + ks * 32 + q * 8);
        #pragma unroll
        for (int t = 0; t < 4; t++) {
            short8 b = *reinterpret_cast<const short8*>(&w1s[(t * 16 + lo) * 264 + ks * 32 + q * 8]);
            acc1[t] = __builtin_amdgcn_mfma_f32_16x16x32_bf16(a, b, acc1[t], 0, 0, 0);
        }
    }
    #pragma unroll
    for (int ks = 0; ks < 4; ks++) {
        short8 a = *reinterpret_cast<const short8*>(rows + ks * 32 + q * 8);
        #pragma unroll
        for (int t = 0; t < 4; t++) {
            short8 b = *reinterpret_cast<const short8*>(&w1s[(t * 16 + lo) * 264 + 128 + ks * 32 + q * 8]);
            acc1[t] = __builtin_amdgcn_mfma_f32_16x16x32_bf16(a, b, acc1[t], 0, 0, 0);
        }
    }
    #pragma unroll
    for (int t = 0; t < 4; t++)
        #pragma unroll
        for (int rr = 0; rr < 4; rr++)
            Hb[wl][(4 * q + rr) * 72 + t * 16 + lo] = f2bf(silu_f(acc1[t][rr]));
    __syncthreads();

    // ---- L2: H1 @ W2 + b2, K=64 ----
    f32x4 acc2[4];
    #pragma unroll
    for (int t = 0; t < 4; t++) {
        float bb = b2[t * 16 + lo];
        #pragma unroll
        for (int rr = 0; rr < 4; rr++) acc2[t][rr] = bb;
    }
    #pragma unroll
    for (int ks = 0; ks < 2; ks++) {
        short8 a = *reinterpret_cast<const short8*>(&Hb[wl][lo * 72 + ks * 32 + q * 8]);
        #pragma unroll
        for (int t = 0; t < 4; t++) {
            short8 b = *reinterpret_cast<const short8*>(&w2s[(t * 16 + lo) * 72 + ks * 32 + q * 8]);
            acc2[t] = __builtin_amdgcn_mfma_f32_16x16x32_bf16(a, b, acc2[t], 0, 0, 0);
        }
    }
    __syncthreads();
    #pragma unroll
    for (int t = 0; t < 4; t++)
        #pragma unroll
        for (int rr = 0; rr < 4; rr++)
            Hb[wl][(4 * q + rr) * 72 + t * 16 + lo] = f2bf(silu_f(acc2[t][rr]));
    __syncthreads();

    // ---- L3: H2 @ W3 + b3, K=64, 144 padded outputs; W3T B-frags from global ----
    const unsigned short* w3g = Wpk_l + W1T_SH + W2T_SH;
    f32x4 acc3[9];
    #pragma unroll
    for (int t = 0; t < 9; t++) {
        int n = t * 16 + lo;
        float bb = (n < 134) ? b3[n] : 0.0f;
        #pragma unroll
        for (int rr = 0; rr < 4; rr++) acc3[t][rr] = bb;
    }
    #pragma unroll
    for (int ks = 0; ks < 2; ks++) {
        short8 a = *reinterpret_cast<const short8*>(&Hb[wl][lo * 72 + ks * 32 + q * 8]);
        #pragma unroll
        for (int t = 0; t < 9; t++) {
            short8 b = *reinterpret_cast<const short8*>(w3g + (t * 16 + lo) * 72 + ks * 32 + q * 8);
            acc3[t] = __builtin_amdgcn_mfma_f32_16x16x32_bf16(a, b, acc3[t], 0, 0, 0);
        }
    }

    // store smsg (cols 0..127), scaled by C
    #pragma unroll
    for (int t = 0; t < 8; t++) {
        int colc = t * 16 + lo;
        #pragma unroll
        for (int rr = 0; rr < 4; rr++) {
            long erow = eb + 4 * q + rr; if (erow > N_EDGES - 1) erow = N_EDGES - 1;
            smsg[erow * SD + colc] = f2bf(acc3[t][rr] * cel[wb + 4 * q + rr]);
        }
    }
    // stash gv/gr (cols 128..133)
    if (lo < 6) {
        #pragma unroll
        for (int rr = 0; rr < 4; rr++) gb[wl][4 * q + rr][lo] = acc3[8][rr];
    }
    __syncthreads();

    // per-edge tail: vm = (v[src]*gv + r*gr) * C  -> bf16 vmsg
    if (lane < 16) {
        long e = eb + lane; if (e > N_EDGES - 1) e = N_EDGES - 1;
        float Ce = cel[wb + lane];
        int sn = srcl[wb + lane];
        float rv0 = r_e[3 * e], rv1 = r_e[3 * e + 1], rv2 = r_e[3 * e + 2];
        const float* vs = v + (size_t)sn * (VD * 3);
        #pragma unroll
        for (int vi = 0; vi < VD; vi++) {
            float gv = gb[wl][lane][vi], gr = gb[wl][lane][VD + vi];
            vmsg[e * 12 + vi * 3 + 0] = f2bf((vs[vi * 3 + 0] * gv + rv0 * gr) * Ce);
            vmsg[e * 12 + vi * 3 + 1] = f2bf((vs[vi * 3 + 1] * gv + rv1 * gr) * Ce);
            vmsg[e * 12 + vi * 3 + 2] = f2bf((vs[vi * 3 + 2] * gv + rv2 * gr) * Ce);
        }
    }
}

// ---------------- aggregation kernel ----------------
__global__ __launch_bounds__(256) void agg_kernel(
    const unsigned short* __restrict__ smsg, const unsigned short* __restrict__ vmsg,
    const int* __restrict__ offs, const int* __restrict__ eids,
    float* __restrict__ s_agg, float* __restrict__ v_agg)
{
    int wave = blockIdx.x * 4 + (threadIdx.x >> 6);
    int lane = threadIdx.x & 63;
    if (wave >= N_NODES) return;
    int beg = offs[wave], end = offs[wave + 1];
    float a0 = 0.0f, a1 = 0.0f, va = 0.0f;
    const ushort2* sm2 = reinterpret_cast<const ushort2*>(smsg);
    for (int i = beg; i < end; i++) {
        int e = eids[i];
        ushort2 mm = sm2[(size_t)e * 64 + lane];
        a0 += bf2f(mm.x);
        a1 += bf2f(mm.y);
        if (lane < 9) va += bf2f(vmsg[(size_t)e * 12 + lane]);
    }
    s_agg[(size_t)wave * SD + lane * 2]     = a0;
    s_agg[(size_t)wave * SD + lane * 2 + 1] = a1;
    if (lane < 9) v_agg[(size_t)wave * 9 + lane] = va;
}

// ---------------- node kernel ----------------
__global__ __launch_bounds__(256) void node_kernel(
    float* __restrict__ s, float* __restrict__ v, unsigned short* __restrict__ s_bf,
    const float* __restrict__ s_agg, const float* __restrict__ v_agg,
    const float* __restrict__ inv_cnt,
    const float* __restrict__ Wn1, const float* __restrict__ bn1,
    const float* __restrict__ Wn2T, const float* __restrict__ bn2)
{
    int n = blockIdx.x * 256 + threadIdx.x;
    if (n >= N_NODES) return;

    float u[HID];
    #pragma unroll
    for (int j = 0; j < HID; j++) u[j] = bn1[j];

    const float4* s4 = reinterpret_cast<const float4*>(s + (size_t)n * SD);
    for (int i4 = 0; i4 < SD / 4; i4++) {
        fma4x64(u, s4[i4], Wn1 + (size_t)i4 * 4 * HID);
    }
    const float4* a4 = reinterpret_cast<const float4*>(s_agg + (size_t)n * SD);
    for (int i4 = 0; i4 < SD / 4; i4++) {
        fma4x64(u, a4[i4], Wn1 + ((size_t)SD + i4 * 4) * HID);
    }
    #pragma unroll
    for (int j = 0; j < HID; j++) u[j] = silu_f(u[j]);

    float* srow = s + (size_t)n * SD;
    unsigned short* brow = s_bf + (size_t)n * SD;
    float prev = 0.0f;
    for (int j = 0; j < SD; j++) {
        const float* w = Wn2T + (size_t)j * HID;
        float acc = bn2[j];
        #pragma unroll
        for (int k = 0; k < HID; k++) acc += u[k] * w[k];
        float ns = srow[j] + acc;
        srow[j] = ns;
        if (j & 1) {
            ushort2 p; p.x = f2bf(prev); p.y = f2bf(ns);
            *reinterpret_cast<ushort2*>(brow + j - 1) = p;
        } else prev = ns;
    }
    float ic = inv_cnt[n];
    #pragma unroll
    for (int t = 0; t < VD * 3; t++)
        v[(size_t)n * (VD * 3) + t] += v_agg[(size_t)n * 9 + t] * ic;
}

// ---------------- launch ----------------
extern "C" void kernel_launch(void* const* d_in, const int* in_sizes, int n_in,
                              void* d_out, int out_size, void* d_ws, size_t ws_size,
                              hipStream_t stream)
{
    (void)in_sizes; (void)n_in; (void)out_size; (void)ws_size;
    const float* s_in = (const float*)d_in[0];
    const float* v_in = (const float*)d_in[1];
    const int*   ei   = (const int*)d_in[2];
    const float* d_e  = (const float*)d_in[3];
    const float* r_e  = (const float*)d_in[4];
    const float* W1   = (const float*)d_in[5];
    const float* b1   = (const float*)d_in[6];
    const float* W2   = (const float*)d_in[7];
    const float* b2   = (const float*)d_in[8];
    const float* W3   = (const float*)d_in[9];
    const float* b3   = (const float*)d_in[10];
    const float* Wn1  = (const float*)d_in[11];
    const float* bn1  = (const float*)d_in[12];
    const float* Wn2  = (const float*)d_in[13];
    const float* bn2  = (const float*)d_in[14];

    float* s = (float*)d_out;                 // N*SD, updated in place
    float* v = s + (size_t)N_NODES * SD;      // N*VD*3

    // ---- workspace layout ----
    float* ws      = (float*)d_ws;
    float* s_agg   = ws;                                        // N*SD
    float* v_agg   = s_agg + (size_t)N_NODES * SD;              // N*9
    float* cntinv  = v_agg + (size_t)N_NODES * 9;               // N
    float* Cbuf    = cntinv + N_NODES;                          // E
    float* Wn2T    = Cbuf + N_EDGES;                            // DEPTH*128*64
    int*   cnti    = (int*)(Wn2T + (size_t)DEPTH * SD * HID);   // N
    int*   offs    = cnti + N_NODES;                            // N+1
    int*   cursor  = offs + N_NODES + 1;                        // N
    int*   eids    = cursor + N_NODES;                          // E
    int*   bsum    = eids + N_EDGES;                            // 64
    uintptr_t up   = (uintptr_t)(bsum + 64);
    up = (up + 15) & ~(uintptr_t)15;
    unsigned short* s_bf = (unsigned short*)up;                 // N*SD bf16
    unsigned short* Wpk  = s_bf + (size_t)N_NODES * SD;         // DEPTH*WPK_SH
    unsigned short* smsg = Wpk + (size_t)DEPTH * WPK_SH;        // E*128
    unsigned short* vmsg = smsg + (size_t)N_EDGES * SD;         // E*12

    hipMemsetAsync(cnti, 0, sizeof(int) * (size_t)N_NODES, stream);
    hipMemsetAsync(cursor, 0, sizeof(int) * (size_t)N_NODES, stream);

    cast_s_kernel<<<(N_NODES * SD + 255) / 256, 256, 0, stream>>>(s_in, s, s_bf, N_NODES * SD);
    copy_kernel<<<(N_NODES * VD * 3 + 255) / 256, 256, 0, stream>>>(v_in, v, N_NODES * VD * 3);
    prep_edges<<<(N_EDGES + 255) / 256, 256, 0, stream>>>(ei, d_e, Cbuf, cnti);
    inv_cnt_kernel<<<(N_NODES + 255) / 256, 256, 0, stream>>>(cnti, cntinv);

    const int NB = (N_NODES + 1023) / 1024;   // 49
    scan_block<<<NB, 1024, 0, stream>>>(cnti, offs, bsum);
    scan_partials<<<1, 64, 0, stream>>>(bsum, NB, offs + N_NODES);
    scan_apply<<<NB, 1024, 0, stream>>>(offs, bsum);
    build_perm<<<(N_EDGES + 255) / 256, 256, 0, stream>>>(ei, offs, cursor, eids);

    prep_weights<<<(DEPTH * WPK_SH + 255) / 256, 256, 0, stream>>>(W1, W2, W3, Wpk);
    transpose_kernel<<<(DEPTH * HID * SD + 255) / 256, 256, 0, stream>>>(Wn2, Wn2T, HID, SD);

    for (int l = 0; l < DEPTH; l++) {
        edge_mfma<<<(N_EDGES + 63) / 64, 256, 0, stream>>>(
            s_bf, v, ei, d_e, Cbuf, r_e,
            Wpk + (size_t)l * WPK_SH,
            W1 + ((size_t)l * 257 + 256) * 64,
            b1 + (size_t)l * HID, b2 + (size_t)l * HID, b3 + (size_t)l * (SD + 2 * VD),
            smsg, vmsg);
        agg_kernel<<<(N_NODES + 3) / 4, 256, 0, stream>>>(
            smsg, vmsg, offs, eids, s_agg, v_agg);
        node_kernel<<<(N_NODES + 255) / 256, 256, 0, stream>>>(
            s, v, s_bf, s_agg, v_agg, cntinv,
            Wn1 + (size_t)l * 2 * SD * HID, bn1 + (size_t)l * HID,
            Wn2T + (size_t)l * SD * HID,    bn2 + (size_t)l * SD);
    }
}

// Round 4
// 1274.489 us; speedup vs baseline: 12.4101x; 1.4768x over previous
//
#include <hip/hip_runtime.h>
#include <hip/hip_bf16.h>
#include <math.h>

#define N_NODES 50000
#define N_EDGES 500000
#define SD 128
#define VD 3
#define HID 64
#define DEPTH 4

// packed bf16 weight block per layer: W1T(64x264) + W2T(64x72) + W3T(144x72)
#define W1T_SH (64 * 264)
#define W2T_SH (64 * 72)
#define W3T_SH (144 * 72)
#define WPK_SH (W1T_SH + W2T_SH + W3T_SH)   // 31872 shorts per layer

// node weights per layer: Wn1T (64 x 256) + Wn2T (128 x 64)
#define WN1T_SH (64 * 256)
#define WN2T_SH (128 * 64)
#define WN_SH (WN1T_SH + WN2T_SH)           // 24576 shorts per layer

typedef __attribute__((ext_vector_type(8))) short short8;
typedef __attribute__((ext_vector_type(4))) float f32x4;

__device__ __forceinline__ float silu_f(float x) {
    return x / (1.0f + __expf(-x));
}

__device__ __forceinline__ unsigned short f2bf(float x) {
    __hip_bfloat16 h = __float2bfloat16(x);
    return *reinterpret_cast<unsigned short*>(&h);
}

__device__ __forceinline__ float bf2f(unsigned short u) {
    union { unsigned int i; float f; } c; c.i = ((unsigned int)u) << 16;
    return c.f;
}

// ---------------- setup kernels ----------------

__global__ void cast_s_kernel(const float* __restrict__ in, float* __restrict__ out,
                              unsigned short* __restrict__ out_bf, int n) {
    int i = blockIdx.x * blockDim.x + threadIdx.x;
    if (i < n) { float x = in[i]; out[i] = x; out_bf[i] = f2bf(x); }
}

__global__ void copy_kernel(const float* __restrict__ in, float* __restrict__ out, int n) {
    int i = blockIdx.x * blockDim.x + threadIdx.x;
    if (i < n) out[i] = in[i];
}

__global__ void prep_edges(const int* __restrict__ ei, const float* __restrict__ d,
                           float* __restrict__ C, int* __restrict__ cnti) {
    int e = blockIdx.x * blockDim.x + threadIdx.x;
    if (e >= N_EDGES) return;
    float de = d[e];
    float c = 0.5f * (cosf(3.14159265358979323846f * de * (1.0f / 5.0f)) + 1.0f);
    C[e] = (de < 5.0f) ? c : 0.0f;
    atomicAdd(&cnti[ei[e]], 1);
}

__global__ void inv_cnt_kernel(const int* __restrict__ cnti, float* __restrict__ inv_cnt) {
    int i = blockIdx.x * blockDim.x + threadIdx.x;
    if (i < N_NODES) inv_cnt[i] = 1.0f / fmaxf((float)cnti[i], 1.0f);
}

// multi-block scan: phase 1 — per-block exclusive scan + block sums
__global__ __launch_bounds__(1024) void scan_block(const int* __restrict__ cnti,
                                                   int* __restrict__ offs,
                                                   int* __restrict__ bsum) {
    __shared__ int sh[1024];
    int tid = threadIdx.x;
    int idx = blockIdx.x * 1024 + tid;
    int x = (idx < N_NODES) ? cnti[idx] : 0;
    sh[tid] = x;
    __syncthreads();
    for (int off = 1; off < 1024; off <<= 1) {
        int y = (tid >= off) ? sh[tid - off] : 0;
        __syncthreads();
        sh[tid] += y;
        __syncthreads();
    }
    if (idx < N_NODES) offs[idx] = sh[tid] - x;   // exclusive, block-local
    if (tid == 1023) bsum[blockIdx.x] = sh[1023];
}

// phase 2 — scan the block sums serially, write grand total to offs[N]
__global__ void scan_partials(int* __restrict__ bsum, int nb, int* __restrict__ offs_total) {
    if (threadIdx.x == 0 && blockIdx.x == 0) {
        int acc = 0;
        for (int i = 0; i < nb; i++) { int t = bsum[i]; bsum[i] = acc; acc += t; }
        offs_total[0] = acc;
    }
}

// phase 3 — add block offsets
__global__ __launch_bounds__(1024) void scan_apply(int* __restrict__ offs,
                                                   const int* __restrict__ bsum) {
    int idx = blockIdx.x * 1024 + threadIdx.x;
    if (idx < N_NODES) offs[idx] += bsum[blockIdx.x];
}

__global__ void build_perm(const int* __restrict__ ei, const int* __restrict__ offs,
                           int* __restrict__ cursor, int* __restrict__ eids) {
    int e = blockIdx.x * blockDim.x + threadIdx.x;
    if (e >= N_EDGES) return;
    int dst = ei[e];
    int p = offs[dst] + atomicAdd(&cursor[dst], 1);
    eids[p] = e;
}

// pack transposed bf16 weights for the edge MLP:
//   W1T[n][k] (64x264, k<257 valid), W2T[n][k] (64x72, k<64), W3T[n][k] (144x72, n<134,k<64)
__global__ void prep_weights(const float* __restrict__ W1, const float* __restrict__ W2,
                             const float* __restrict__ W3, unsigned short* __restrict__ Wpk) {
    int idx = blockIdx.x * blockDim.x + threadIdx.x;
    if (idx >= DEPTH * WPK_SH) return;
    int l = idx / WPK_SH;
    int j = idx - l * WPK_SH;
    float val = 0.0f;
    if (j < W1T_SH) {
        int n = j / 264, k = j - n * 264;
        if (k < 257) val = W1[((size_t)l * 257 + k) * 64 + n];
    } else if (j < W1T_SH + W2T_SH) {
        int jj = j - W1T_SH;
        int n = jj / 72, k = jj - n * 72;
        if (k < 64) val = W2[((size_t)l * 64 + k) * 64 + n];
    } else {
        int jj = j - W1T_SH - W2T_SH;
        int n = jj / 72, k = jj - n * 72;
        if (n < 134 && k < 64) val = W3[((size_t)l * 64 + k) * 134 + n];
    }
    Wpk[idx] = f2bf(val);
}

// pack transposed bf16 node-MLP weights: Wn1T[n][k] (64x256), Wn2T[n][k] (128x64)
__global__ void prep_node_weights(const float* __restrict__ Wn1, const float* __restrict__ Wn2,
                                  unsigned short* __restrict__ Wnpk) {
    int idx = blockIdx.x * blockDim.x + threadIdx.x;
    if (idx >= DEPTH * WN_SH) return;
    int l = idx / WN_SH;
    int j = idx - l * WN_SH;
    float val;
    if (j < WN1T_SH) {
        int n = j / 256, k = j - n * 256;
        val = Wn1[((size_t)l * 256 + k) * 64 + n];
    } else {
        int jj = j - WN1T_SH;
        int n = jj / 64, k = jj - n * 64;
        val = Wn2[((size_t)l * 64 + k) * 128 + n];
    }
    Wnpk[idx] = f2bf(val);
}

// ---------------- MFMA edge kernel ----------------
// block = 256 threads = 4 waves; wave handles 16 edges through the 3-layer MLP.
// A-frag: lane holds A[m=lane&15][k=quad*8+j]; B-frag: B[n=lane&15][k=quad*8+j]
// from transposed weights; C/D: col=lane&15, row=quad*4+reg.
__global__ __launch_bounds__(256) void edge_mfma(
    const unsigned short* __restrict__ s_bf, const float* __restrict__ v,
    const int* __restrict__ ei, const float* __restrict__ d_e,
    const float* __restrict__ Cbuf, const float* __restrict__ r_e,
    const unsigned short* __restrict__ Wpk_l,   // this layer's packed bf16 weights
    const float* __restrict__ W1r,              // fp32 W1 row 256 (the d feature)
    const float* __restrict__ b1, const float* __restrict__ b2,
    const float* __restrict__ b3,
    unsigned short* __restrict__ smsg, unsigned short* __restrict__ vmsg)
{
    __shared__ __align__(16) unsigned short w1s[W1T_SH];   // 33792 B
    __shared__ __align__(16) unsigned short w2s[W2T_SH];   //  9216 B
    __shared__ __align__(16) unsigned short Hb[4][16 * 72]; //  9216 B (H1 then H2)
    __shared__ int dstl[64], srcl[64];
    __shared__ float dcl[64], cel[64];
    __shared__ float gb[4][16][6];

    const int tid  = threadIdx.x;
    const int wl   = tid >> 6;
    const int lane = tid & 63;
    const int lo   = lane & 15;
    const int q    = lane >> 4;
    const int wb   = wl * 16;
    const long eb  = (long)blockIdx.x * 64 + wb;   // wave's first edge

    // stage W1T + W2T into LDS (16B vector copies)
    {
        const short8* g  = reinterpret_cast<const short8*>(Wpk_l);
        short8* l1 = reinterpret_cast<short8*>(w1s);
        short8* l2 = reinterpret_cast<short8*>(w2s);
        for (int i = tid; i < W1T_SH / 8; i += 256) l1[i] = g[i];
        for (int i = tid; i < W2T_SH / 8; i += 256) l2[i] = g[W1T_SH / 8 + i];
    }
    if (lane < 16) {
        long e = eb + lane; if (e > N_EDGES - 1) e = N_EDGES - 1;
        dstl[wb + lane] = ei[e];
        srcl[wb + lane] = ei[N_EDGES + e];
        dcl[wb + lane]  = d_e[e];
        cel[wb + lane]  = Cbuf[e];
    }
    __syncthreads();

    // ---- L1: [s_dst | s_src | d] @ W1 + b1, K=256 via MFMA + d on VALU ----
    f32x4 acc1[4];
    #pragma unroll
    for (int t = 0; t < 4; t++) {
        int n = t * 16 + lo;
        float bb = b1[n], wr = W1r[n];
        #pragma unroll
        for (int rr = 0; rr < 4; rr++)
            acc1[t][rr] = bb + dcl[wb + 4 * q + rr] * wr;
    }
    const unsigned short* rowd = s_bf + (size_t)dstl[wb + lo] * SD;
    const unsigned short* rows = s_bf + (size_t)srcl[wb + lo] * SD;
    #pragma unroll
    for (int ks = 0; ks < 4; ks++) {
        short8 a = *reinterpret_cast<const short8*>(rowd + ks * 32 + q * 8);
        #pragma unroll
        for (int t = 0; t < 4; t++) {
            short8 b = *reinterpret_cast<const short8*>(&w1s[(t * 16 + lo) * 264 + ks * 32 + q * 8]);
            acc1[t] = __builtin_amdgcn_mfma_f32_16x16x32_bf16(a, b, acc1[t], 0, 0, 0);
        }
    }
    #pragma unroll
    for (int ks = 0; ks < 4; ks++) {
        short8 a = *reinterpret_cast<const short8*>(rows + ks * 32 + q * 8);
        #pragma unroll
        for (int t = 0; t < 4; t++) {
            short8 b = *reinterpret_cast<const short8*>(&w1s[(t * 16 + lo) * 264 + 128 + ks * 32 + q * 8]);
            acc1[t] = __builtin_amdgcn_mfma_f32_16x16x32_bf16(a, b, acc1[t], 0, 0, 0);
        }
    }
    #pragma unroll
    for (int t = 0; t < 4; t++)
        #pragma unroll
        for (int rr = 0; rr < 4; rr++)
            Hb[wl][(4 * q + rr) * 72 + t * 16 + lo] = f2bf(silu_f(acc1[t][rr]));
    __syncthreads();

    // ---- L2: H1 @ W2 + b2, K=64 ----
    f32x4 acc2[4];
    #pragma unroll
    for (int t = 0; t < 4; t++) {
        float bb = b2[t * 16 + lo];
        #pragma unroll
        for (int rr = 0; rr < 4; rr++) acc2[t][rr] = bb;
    }
    #pragma unroll
    for (int ks = 0; ks < 2; ks++) {
        short8 a = *reinterpret_cast<const short8*>(&Hb[wl][lo * 72 + ks * 32 + q * 8]);
        #pragma unroll
        for (int t = 0; t < 4; t++) {
            short8 b = *reinterpret_cast<const short8*>(&w2s[(t * 16 + lo) * 72 + ks * 32 + q * 8]);
            acc2[t] = __builtin_amdgcn_mfma_f32_16x16x32_bf16(a, b, acc2[t], 0, 0, 0);
        }
    }
    __syncthreads();
    #pragma unroll
    for (int t = 0; t < 4; t++)
        #pragma unroll
        for (int rr = 0; rr < 4; rr++)
            Hb[wl][(4 * q + rr) * 72 + t * 16 + lo] = f2bf(silu_f(acc2[t][rr]));
    __syncthreads();

    // ---- L3: H2 @ W3 + b3, K=64, 144 padded outputs; W3T B-frags from global ----
    const unsigned short* w3g = Wpk_l + W1T_SH + W2T_SH;
    f32x4 acc3[9];
    #pragma unroll
    for (int t = 0; t < 9; t++) {
        int n = t * 16 + lo;
        float bb = (n < 134) ? b3[n] : 0.0f;
        #pragma unroll
        for (int rr = 0; rr < 4; rr++) acc3[t][rr] = bb;
    }
    #pragma unroll
    for (int ks = 0; ks < 2; ks++) {
        short8 a = *reinterpret_cast<const short8*>(&Hb[wl][lo * 72 + ks * 32 + q * 8]);
        #pragma unroll
        for (int t = 0; t < 9; t++) {
            short8 b = *reinterpret_cast<const short8*>(w3g + (t * 16 + lo) * 72 + ks * 32 + q * 8);
            acc3[t] = __builtin_amdgcn_mfma_f32_16x16x32_bf16(a, b, acc3[t], 0, 0, 0);
        }
    }

    // store smsg (cols 0..127), scaled by C
    #pragma unroll
    for (int t = 0; t < 8; t++) {
        int colc = t * 16 + lo;
        #pragma unroll
        for (int rr = 0; rr < 4; rr++) {
            long erow = eb + 4 * q + rr; if (erow > N_EDGES - 1) erow = N_EDGES - 1;
            smsg[erow * SD + colc] = f2bf(acc3[t][rr] * cel[wb + 4 * q + rr]);
        }
    }
    // stash gv/gr (cols 128..133)
    if (lo < 6) {
        #pragma unroll
        for (int rr = 0; rr < 4; rr++) gb[wl][4 * q + rr][lo] = acc3[8][rr];
    }
    __syncthreads();

    // per-edge tail: vm = (v[src]*gv + r*gr) * C  -> bf16 vmsg
    if (lane < 16) {
        long e = eb + lane; if (e > N_EDGES - 1) e = N_EDGES - 1;
        float Ce = cel[wb + lane];
        int sn = srcl[wb + lane];
        float rv0 = r_e[3 * e], rv1 = r_e[3 * e + 1], rv2 = r_e[3 * e + 2];
        const float* vs = v + (size_t)sn * (VD * 3);
        #pragma unroll
        for (int vi = 0; vi < VD; vi++) {
            float gv = gb[wl][lane][vi], gr = gb[wl][lane][VD + vi];
            vmsg[e * 12 + vi * 3 + 0] = f2bf((vs[vi * 3 + 0] * gv + rv0 * gr) * Ce);
            vmsg[e * 12 + vi * 3 + 1] = f2bf((vs[vi * 3 + 1] * gv + rv1 * gr) * Ce);
            vmsg[e * 12 + vi * 3 + 2] = f2bf((vs[vi * 3 + 2] * gv + rv2 * gr) * Ce);
        }
    }
}

// ---------------- aggregation kernel ----------------
// One wave per node: gather bf16 message rows via CSR, sum in fp32,
// write s_agg as bf16 (feeds node-MLP MFMA) and v_agg as fp32.
__global__ __launch_bounds__(256) void agg_kernel(
    const unsigned short* __restrict__ smsg, const unsigned short* __restrict__ vmsg,
    const int* __restrict__ offs, const int* __restrict__ eids,
    unsigned short* __restrict__ s_agg_bf, float* __restrict__ v_agg)
{
    int wave = blockIdx.x * 4 + (threadIdx.x >> 6);
    int lane = threadIdx.x & 63;
    if (wave >= N_NODES) return;
    int beg = offs[wave], end = offs[wave + 1];
    float a0 = 0.0f, a1 = 0.0f, va = 0.0f;
    const ushort2* sm2 = reinterpret_cast<const ushort2*>(smsg);
    for (int i = beg; i < end; i++) {
        int e = eids[i];
        ushort2 mm = sm2[(size_t)e * 64 + lane];
        a0 += bf2f(mm.x);
        a1 += bf2f(mm.y);
        if (lane < 9) va += bf2f(vmsg[(size_t)e * 12 + lane]);
    }
    ushort2 o; o.x = f2bf(a0); o.y = f2bf(a1);
    *reinterpret_cast<ushort2*>(s_agg_bf + (size_t)wave * SD + lane * 2) = o;
    if (lane < 9) v_agg[(size_t)wave * 9 + lane] = va;
}

// ---------------- MFMA node kernel ----------------
// wave = 16 nodes: u = silu([s | s_agg] @ Wn1 + bn1) (K=256),
// s += u @ Wn2 + bn2 (K=64 -> 128 cols). Same fragment pattern as edge_mfma.
__global__ __launch_bounds__(256) void node_mfma(
    float* __restrict__ s, float* __restrict__ v, unsigned short* __restrict__ s_bf,
    const unsigned short* __restrict__ s_agg_bf, const float* __restrict__ v_agg,
    const float* __restrict__ inv_cnt,
    const unsigned short* __restrict__ Wn_l,   // this layer's packed Wn1T+Wn2T
    const float* __restrict__ bn1, const float* __restrict__ bn2)
{
    __shared__ __align__(16) unsigned short Hb[4][16 * 72];   // 9216 B

    const int tid  = threadIdx.x;
    const int wl   = tid >> 6;
    const int lane = tid & 63;
    const int lo   = lane & 15;
    const int q    = lane >> 4;
    const int nb   = blockIdx.x * 64 + wl * 16;   // wave's first node

    int na = nb + lo; if (na > N_NODES - 1) na = N_NODES - 1;
    const unsigned short* rs = s_bf     + (size_t)na * SD;
    const unsigned short* ra = s_agg_bf + (size_t)na * SD;

    // ---- L1: [s | s_agg] @ Wn1 + bn1 ----
    f32x4 acc1[4];
    #pragma unroll
    for (int t = 0; t < 4; t++) {
        float bb = bn1[t * 16 + lo];
        #pragma unroll
        for (int rr = 0; rr < 4; rr++) acc1[t][rr] = bb;
    }
    #pragma unroll
    for (int ks = 0; ks < 4; ks++) {
        short8 a = *reinterpret_cast<const short8*>(rs + ks * 32 + q * 8);
        #pragma unroll
        for (int t = 0; t < 4; t++) {
            short8 b = *reinterpret_cast<const short8*>(Wn_l + (t * 16 + lo) * 256 + ks * 32 + q * 8);
            acc1[t] = __builtin_amdgcn_mfma_f32_16x16x32_bf16(a, b, acc1[t], 0, 0, 0);
        }
    }
    #pragma unroll
    for (int ks = 0; ks < 4; ks++) {
        short8 a = *reinterpret_cast<const short8*>(ra + ks * 32 + q * 8);
        #pragma unroll
        for (int t = 0; t < 4; t++) {
            short8 b = *reinterpret_cast<const short8*>(Wn_l + (t * 16 + lo) * 256 + 128 + ks * 32 + q * 8);
            acc1[t] = __builtin_amdgcn_mfma_f32_16x16x32_bf16(a, b, acc1[t], 0, 0, 0);
        }
    }
    #pragma unroll
    for (int t = 0; t < 4; t++)
        #pragma unroll
        for (int rr = 0; rr < 4; rr++)
            Hb[wl][(4 * q + rr) * 72 + t * 16 + lo] = f2bf(silu_f(acc1[t][rr]));
    __syncthreads();

    // ---- L2: u @ Wn2 + bn2, K=64, 128 cols ----
    const unsigned short* w2g = Wn_l + WN1T_SH;
    f32x4 acc2[8];
    #pragma unroll
    for (int t = 0; t < 8; t++) {
        float bb = bn2[t * 16 + lo];
        #pragma unroll
        for (int rr = 0; rr < 4; rr++) acc2[t][rr] = bb;
    }
    #pragma unroll
    for (int ks = 0; ks < 2; ks++) {
        short8 a = *reinterpret_cast<const short8*>(&Hb[wl][lo * 72 + ks * 32 + q * 8]);
        #pragma unroll
        for (int t = 0; t < 8; t++) {
            short8 b = *reinterpret_cast<const short8*>(w2g + (t * 16 + lo) * 64 + ks * 32 + q * 8);
            acc2[t] = __builtin_amdgcn_mfma_f32_16x16x32_bf16(a, b, acc2[t], 0, 0, 0);
        }
    }

    // ---- residual add + store fp32 s and bf16 s_bf ----
    #pragma unroll
    for (int t = 0; t < 8; t++) {
        int col = t * 16 + lo;
        #pragma unroll
        for (int rr = 0; rr < 4; rr++) {
            int node = nb + 4 * q + rr;
            if (node < N_NODES) {
                size_t idx = (size_t)node * SD + col;
                float ns = s[idx] + acc2[t][rr];
                s[idx] = ns;
                s_bf[idx] = f2bf(ns);
            }
        }
    }

    // ---- v update: one node per lane (lanes 0..15) ----
    if (lane < 16) {
        int node = nb + lane;
        if (node < N_NODES) {
            float ic = inv_cnt[node];
            #pragma unroll
            for (int t = 0; t < VD * 3; t++)
                v[(size_t)node * 9 + t] += v_agg[(size_t)node * 9 + t] * ic;
        }
    }
}

// ---------------- launch ----------------
extern "C" void kernel_launch(void* const* d_in, const int* in_sizes, int n_in,
                              void* d_out, int out_size, void* d_ws, size_t ws_size,
                              hipStream_t stream)
{
    (void)in_sizes; (void)n_in; (void)out_size; (void)ws_size;
    const float* s_in = (const float*)d_in[0];
    const float* v_in = (const float*)d_in[1];
    const int*   ei   = (const int*)d_in[2];
    const float* d_e  = (const float*)d_in[3];
    const float* r_e  = (const float*)d_in[4];
    const float* W1   = (const float*)d_in[5];
    const float* b1   = (const float*)d_in[6];
    const float* W2   = (const float*)d_in[7];
    const float* b2   = (const float*)d_in[8];
    const float* W3   = (const float*)d_in[9];
    const float* b3   = (const float*)d_in[10];
    const float* Wn1  = (const float*)d_in[11];
    const float* bn1  = (const float*)d_in[12];
    const float* Wn2  = (const float*)d_in[13];
    const float* bn2  = (const float*)d_in[14];

    float* s = (float*)d_out;                 // N*SD, updated in place
    float* v = s + (size_t)N_NODES * SD;      // N*VD*3

    // ---- workspace layout ----
    float* ws      = (float*)d_ws;
    float* v_agg   = ws;                                        // N*9
    float* cntinv  = v_agg + (size_t)N_NODES * 9;               // N
    float* Cbuf    = cntinv + N_NODES;                          // E
    int*   cnti    = (int*)(Cbuf + N_EDGES);                    // N
    int*   offs    = cnti + N_NODES;                            // N+1
    int*   cursor  = offs + N_NODES + 1;                        // N
    int*   eids    = cursor + N_NODES;                          // E
    int*   bsum    = eids + N_EDGES;                            // 64
    uintptr_t up   = (uintptr_t)(bsum + 64);
    up = (up + 15) & ~(uintptr_t)15;
    unsigned short* s_bf     = (unsigned short*)up;             // N*SD
    unsigned short* s_agg_bf = s_bf + (size_t)N_NODES * SD;     // N*SD
    unsigned short* Wpk      = s_agg_bf + (size_t)N_NODES * SD; // DEPTH*WPK_SH
    unsigned short* Wnpk     = Wpk + (size_t)DEPTH * WPK_SH;    // DEPTH*WN_SH
    unsigned short* smsg     = Wnpk + (size_t)DEPTH * WN_SH;    // E*128
    unsigned short* vmsg     = smsg + (size_t)N_EDGES * SD;     // E*12

    hipMemsetAsync(cnti, 0, sizeof(int) * (size_t)N_NODES, stream);
    hipMemsetAsync(cursor, 0, sizeof(int) * (size_t)N_NODES, stream);

    cast_s_kernel<<<(N_NODES * SD + 255) / 256, 256, 0, stream>>>(s_in, s, s_bf, N_NODES * SD);
    copy_kernel<<<(N_NODES * VD * 3 + 255) / 256, 256, 0, stream>>>(v_in, v, N_NODES * VD * 3);
    prep_edges<<<(N_EDGES + 255) / 256, 256, 0, stream>>>(ei, d_e, Cbuf, cnti);
    inv_cnt_kernel<<<(N_NODES + 255) / 256, 256, 0, stream>>>(cnti, cntinv);

    const int NB = (N_NODES + 1023) / 1024;   // 49
    scan_block<<<NB, 1024, 0, stream>>>(cnti, offs, bsum);
    scan_partials<<<1, 64, 0, stream>>>(bsum, NB, offs + N_NODES);
    scan_apply<<<NB, 1024, 0, stream>>>(offs, bsum);
    build_perm<<<(N_EDGES + 255) / 256, 256, 0, stream>>>(ei, offs, cursor, eids);

    prep_weights<<<(DEPTH * WPK_SH + 255) / 256, 256, 0, stream>>>(W1, W2, W3, Wpk);
    prep_node_weights<<<(DEPTH * WN_SH + 255) / 256, 256, 0, stream>>>(Wn1, Wn2, Wnpk);

    for (int l = 0; l < DEPTH; l++) {
        edge_mfma<<<(N_EDGES + 63) / 64, 256, 0, stream>>>(
            s_bf, v, ei, d_e, Cbuf, r_e,
            Wpk + (size_t)l * WPK_SH,
            W1 + ((size_t)l * 257 + 256) * 64,
            b1 + (size_t)l * HID, b2 + (size_t)l * HID, b3 + (size_t)l * (SD + 2 * VD),
            smsg, vmsg);
        agg_kernel<<<(N_NODES + 3) / 4, 256, 0, stream>>>(
            smsg, vmsg, offs, eids, s_agg_bf, v_agg);
        node_mfma<<<(N_NODES + 63) / 64, 256, 0, stream>>>(
            s, v, s_bf, s_agg_bf, v_agg, cntinv,
            Wnpk + (size_t)l * WN_SH,
            bn1 + (size_t)l * HID, bn2 + (size_t)l * SD);
    }
}

// Round 5
// 1199.916 us; speedup vs baseline: 13.1814x; 1.0621x over previous
//
#include <hip/hip_runtime.h>
#include <hip/hip_bf16.h>
#include <math.h>

#define N_NODES 50000
#define N_EDGES 500000
#define SD 128
#define VD 3
#define HID 64
#define DEPTH 4

// packed bf16 weight block per layer: W1T(64x264) + W2T(64x72) + W3T(144x72)
#define W1T_SH (64 * 264)
#define W2T_SH (64 * 72)
#define W3T_SH (144 * 72)
#define WPK_SH (W1T_SH + W2T_SH + W3T_SH)   // 31872 shorts per layer

// node weights per layer: Wn1T (64 x 256) + Wn2T (128 x 64)
#define WN1T_SH (64 * 256)
#define WN2T_SH (128 * 64)
#define WN_SH (WN1T_SH + WN2T_SH)           // 24576 shorts per layer

typedef __attribute__((ext_vector_type(8))) short short8;
typedef __attribute__((ext_vector_type(4))) float f32x4;

__device__ __forceinline__ float silu_f(float x) {
    return x / (1.0f + __expf(-x));
}

__device__ __forceinline__ unsigned short f2bf(float x) {
    __hip_bfloat16 h = __float2bfloat16(x);
    return *reinterpret_cast<unsigned short*>(&h);
}

__device__ __forceinline__ float bf2f(unsigned short u) {
    union { unsigned int i; float f; } c; c.i = ((unsigned int)u) << 16;
    return c.f;
}

// ---------------- setup kernels ----------------

__global__ void cast_s_kernel(const float* __restrict__ in, float* __restrict__ out,
                              unsigned short* __restrict__ out_bf, int n) {
    int i = blockIdx.x * blockDim.x + threadIdx.x;
    if (i < n) { float x = in[i]; out[i] = x; out_bf[i] = f2bf(x); }
}

__global__ void copy_kernel(const float* __restrict__ in, float* __restrict__ out, int n) {
    int i = blockIdx.x * blockDim.x + threadIdx.x;
    if (i < n) out[i] = in[i];
}

__global__ void prep_edges(const int* __restrict__ ei, const float* __restrict__ d,
                           float* __restrict__ C, int* __restrict__ cnti) {
    int e = blockIdx.x * blockDim.x + threadIdx.x;
    if (e >= N_EDGES) return;
    float de = d[e];
    float c = 0.5f * (cosf(3.14159265358979323846f * de * (1.0f / 5.0f)) + 1.0f);
    C[e] = (de < 5.0f) ? c : 0.0f;
    atomicAdd(&cnti[ei[e]], 1);
}

__global__ void inv_cnt_kernel(const int* __restrict__ cnti, float* __restrict__ inv_cnt) {
    int i = blockIdx.x * blockDim.x + threadIdx.x;
    if (i < N_NODES) inv_cnt[i] = 1.0f / fmaxf((float)cnti[i], 1.0f);
}

// multi-block scan: phase 1 — per-block exclusive scan + block sums
__global__ __launch_bounds__(1024) void scan_block(const int* __restrict__ cnti,
                                                   int* __restrict__ offs,
                                                   int* __restrict__ bsum) {
    __shared__ int sh[1024];
    int tid = threadIdx.x;
    int idx = blockIdx.x * 1024 + tid;
    int x = (idx < N_NODES) ? cnti[idx] : 0;
    sh[tid] = x;
    __syncthreads();
    for (int off = 1; off < 1024; off <<= 1) {
        int y = (tid >= off) ? sh[tid - off] : 0;
        __syncthreads();
        sh[tid] += y;
        __syncthreads();
    }
    if (idx < N_NODES) offs[idx] = sh[tid] - x;   // exclusive, block-local
    if (tid == 1023) bsum[blockIdx.x] = sh[1023];
}

__global__ void scan_partials(int* __restrict__ bsum, int nb, int* __restrict__ offs_total) {
    if (threadIdx.x == 0 && blockIdx.x == 0) {
        int acc = 0;
        for (int i = 0; i < nb; i++) { int t = bsum[i]; bsum[i] = acc; acc += t; }
        offs_total[0] = acc;
    }
}

__global__ __launch_bounds__(1024) void scan_apply(int* __restrict__ offs,
                                                   const int* __restrict__ bsum) {
    int idx = blockIdx.x * 1024 + threadIdx.x;
    if (idx < N_NODES) offs[idx] += bsum[blockIdx.x];
}

__global__ void build_perm(const int* __restrict__ ei, const int* __restrict__ offs,
                           int* __restrict__ cursor, int* __restrict__ eids) {
    int e = blockIdx.x * blockDim.x + threadIdx.x;
    if (e >= N_EDGES) return;
    int dst = ei[e];
    int p = offs[dst] + atomicAdd(&cursor[dst], 1);
    eids[p] = e;
}

// permute per-edge data into CSR (dst-sorted) order
__global__ void permute_edges(const int* __restrict__ ei, const float* __restrict__ d,
                              const float* __restrict__ C, const float* __restrict__ r,
                              const int* __restrict__ eids,
                              int* __restrict__ dst_s, int* __restrict__ src_s,
                              float* __restrict__ d_s, float* __restrict__ C_s,
                              float* __restrict__ r_s) {
    int p = blockIdx.x * blockDim.x + threadIdx.x;
    if (p >= N_EDGES) return;
    int e = eids[p];
    dst_s[p] = ei[e];
    src_s[p] = ei[N_EDGES + e];
    d_s[p] = d[e];
    C_s[p] = C[e];
    r_s[3 * (size_t)p + 0] = r[3 * (size_t)e + 0];
    r_s[3 * (size_t)p + 1] = r[3 * (size_t)e + 1];
    r_s[3 * (size_t)p + 2] = r[3 * (size_t)e + 2];
}

// pack transposed bf16 weights for the edge MLP
__global__ void prep_weights(const float* __restrict__ W1, const float* __restrict__ W2,
                             const float* __restrict__ W3, unsigned short* __restrict__ Wpk) {
    int idx = blockIdx.x * blockDim.x + threadIdx.x;
    if (idx >= DEPTH * WPK_SH) return;
    int l = idx / WPK_SH;
    int j = idx - l * WPK_SH;
    float val = 0.0f;
    if (j < W1T_SH) {
        int n = j / 264, k = j - n * 264;
        if (k < 257) val = W1[((size_t)l * 257 + k) * 64 + n];
    } else if (j < W1T_SH + W2T_SH) {
        int jj = j - W1T_SH;
        int n = jj / 72, k = jj - n * 72;
        if (k < 64) val = W2[((size_t)l * 64 + k) * 64 + n];
    } else {
        int jj = j - W1T_SH - W2T_SH;
        int n = jj / 72, k = jj - n * 72;
        if (n < 134 && k < 64) val = W3[((size_t)l * 64 + k) * 134 + n];
    }
    Wpk[idx] = f2bf(val);
}

// pack transposed bf16 node-MLP weights: Wn1T[n][k] (64x256), Wn2T[n][k] (128x64)
__global__ void prep_node_weights(const float* __restrict__ Wn1, const float* __restrict__ Wn2,
                                  unsigned short* __restrict__ Wnpk) {
    int idx = blockIdx.x * blockDim.x + threadIdx.x;
    if (idx >= DEPTH * WN_SH) return;
    int l = idx / WN_SH;
    int j = idx - l * WN_SH;
    float val;
    if (j < WN1T_SH) {
        int n = j / 256, k = j - n * 256;
        val = Wn1[((size_t)l * 256 + k) * 64 + n];
    } else {
        int jj = j - WN1T_SH;
        int n = jj / 64, k = jj - n * 64;
        val = Wn2[((size_t)l * 64 + k) * 128 + n];
    }
    Wnpk[idx] = f2bf(val);
}

// ---------------- MFMA edge kernel (CSR-sorted, single-wave blocks) ----------------
// One wave per block processes 16 consecutive CSR positions. Weights read
// directly from global (L1/L2-resident); LDS only for the H layout transform.
// A-frag: lane holds A[m=lane&15][k=q*8+j]; B-frag: B[n=lane&15][k=q*8+j];
// C/D: col=lane&15, row=q*4+reg.
__global__ __launch_bounds__(64, 4) void edge_mfma(
    const unsigned short* __restrict__ s_bf, const float* __restrict__ v,
    const int* __restrict__ dst_s, const int* __restrict__ src_s,
    const float* __restrict__ d_s, const float* __restrict__ C_s,
    const float* __restrict__ r_s,
    const unsigned short* __restrict__ Wpk_l,
    const float* __restrict__ W1r,              // fp32 W1 row 256 (the d feature)
    const float* __restrict__ b1, const float* __restrict__ b2,
    const float* __restrict__ b3,
    unsigned short* __restrict__ smsg, unsigned short* __restrict__ vmsg)
{
    __shared__ __align__(16) unsigned short Hb[16 * 72];   // 2304 B
    __shared__ float gb[16][6];

    const int lane = threadIdx.x & 63;
    const int lo   = lane & 15;
    const int q    = lane >> 4;
    const long eb  = (long)blockIdx.x * 16;   // E % 16 == 0, no clamps needed

    const unsigned short* rowd = s_bf + (size_t)dst_s[eb + lo] * SD;
    const unsigned short* rows = s_bf + (size_t)src_s[eb + lo] * SD;

    float dd[4], ce[4];
    #pragma unroll
    for (int rr = 0; rr < 4; rr++) {
        dd[rr] = d_s[eb + 4 * q + rr];
        ce[rr] = C_s[eb + 4 * q + rr];
    }

    // ---- L1: [s_dst | s_src | d] @ W1 + b1, K=256 via MFMA + d on VALU ----
    f32x4 acc1[4];
    #pragma unroll
    for (int t = 0; t < 4; t++) {
        int n = t * 16 + lo;
        float bb = b1[n], wr = W1r[n];
        #pragma unroll
        for (int rr = 0; rr < 4; rr++)
            acc1[t][rr] = bb + dd[rr] * wr;
    }
    #pragma unroll
    for (int ks = 0; ks < 4; ks++) {
        short8 a = *reinterpret_cast<const short8*>(rowd + ks * 32 + q * 8);
        #pragma unroll
        for (int t = 0; t < 4; t++) {
            short8 b = *reinterpret_cast<const short8*>(Wpk_l + (t * 16 + lo) * 264 + ks * 32 + q * 8);
            acc1[t] = __builtin_amdgcn_mfma_f32_16x16x32_bf16(a, b, acc1[t], 0, 0, 0);
        }
    }
    #pragma unroll
    for (int ks = 0; ks < 4; ks++) {
        short8 a = *reinterpret_cast<const short8*>(rows + ks * 32 + q * 8);
        #pragma unroll
        for (int t = 0; t < 4; t++) {
            short8 b = *reinterpret_cast<const short8*>(Wpk_l + (t * 16 + lo) * 264 + 128 + ks * 32 + q * 8);
            acc1[t] = __builtin_amdgcn_mfma_f32_16x16x32_bf16(a, b, acc1[t], 0, 0, 0);
        }
    }
    #pragma unroll
    for (int t = 0; t < 4; t++)
        #pragma unroll
        for (int rr = 0; rr < 4; rr++)
            Hb[(4 * q + rr) * 72 + t * 16 + lo] = f2bf(silu_f(acc1[t][rr]));
    __syncthreads();

    // ---- L2: H1 @ W2 + b2, K=64 ----
    const unsigned short* w2g = Wpk_l + W1T_SH;
    f32x4 acc2[4];
    #pragma unroll
    for (int t = 0; t < 4; t++) {
        float bb = b2[t * 16 + lo];
        #pragma unroll
        for (int rr = 0; rr < 4; rr++) acc2[t][rr] = bb;
    }
    #pragma unroll
    for (int ks = 0; ks < 2; ks++) {
        short8 a = *reinterpret_cast<const short8*>(&Hb[lo * 72 + ks * 32 + q * 8]);
        #pragma unroll
        for (int t = 0; t < 4; t++) {
            short8 b = *reinterpret_cast<const short8*>(w2g + (t * 16 + lo) * 72 + ks * 32 + q * 8);
            acc2[t] = __builtin_amdgcn_mfma_f32_16x16x32_bf16(a, b, acc2[t], 0, 0, 0);
        }
    }
    __syncthreads();
    #pragma unroll
    for (int t = 0; t < 4; t++)
        #pragma unroll
        for (int rr = 0; rr < 4; rr++)
            Hb[(4 * q + rr) * 72 + t * 16 + lo] = f2bf(silu_f(acc2[t][rr]));
    __syncthreads();

    // ---- L3: H2 @ W3 + b3, K=64, 144 padded outputs ----
    const unsigned short* w3g = Wpk_l + W1T_SH + W2T_SH;
    f32x4 acc3[9];
    #pragma unroll
    for (int t = 0; t < 9; t++) {
        int n = t * 16 + lo;
        float bb = (n < 134) ? b3[n] : 0.0f;
        #pragma unroll
        for (int rr = 0; rr < 4; rr++) acc3[t][rr] = bb;
    }
    #pragma unroll
    for (int ks = 0; ks < 2; ks++) {
        short8 a = *reinterpret_cast<const short8*>(&Hb[lo * 72 + ks * 32 + q * 8]);
        #pragma unroll
        for (int t = 0; t < 9; t++) {
            short8 b = *reinterpret_cast<const short8*>(w3g + (t * 16 + lo) * 72 + ks * 32 + q * 8);
            acc3[t] = __builtin_amdgcn_mfma_f32_16x16x32_bf16(a, b, acc3[t], 0, 0, 0);
        }
    }

    // store smsg (cols 0..127) at the SORTED position, scaled by C
    #pragma unroll
    for (int t = 0; t < 8; t++) {
        int colc = t * 16 + lo;
        #pragma unroll
        for (int rr = 0; rr < 4; rr++) {
            long erow = eb + 4 * q + rr;
            smsg[erow * SD + colc] = f2bf(acc3[t][rr] * ce[rr]);
        }
    }
    // stash gv/gr (cols 128..133)
    if (lo < 6) {
        #pragma unroll
        for (int rr = 0; rr < 4; rr++) gb[4 * q + rr][lo] = acc3[8][rr];
    }
    __syncthreads();

    // per-edge tail: vm = (v[src]*gv + r*gr) * C -> bf16 vmsg (sorted position)
    if (lane < 16) {
        long e = eb + lane;
        float Ce = C_s[e];
        int sn = src_s[e];
        float rv0 = r_s[3 * e], rv1 = r_s[3 * e + 1], rv2 = r_s[3 * e + 2];
        const float* vs = v + (size_t)sn * (VD * 3);
        #pragma unroll
        for (int vi = 0; vi < VD; vi++) {
            float gv = gb[lane][vi], gr = gb[lane][VD + vi];
            vmsg[e * 12 + vi * 3 + 0] = f2bf((vs[vi * 3 + 0] * gv + rv0 * gr) * Ce);
            vmsg[e * 12 + vi * 3 + 1] = f2bf((vs[vi * 3 + 1] * gv + rv1 * gr) * Ce);
            vmsg[e * 12 + vi * 3 + 2] = f2bf((vs[vi * 3 + 2] * gv + rv2 * gr) * Ce);
        }
    }
}

// ---------------- aggregation kernel (streaming: smsg is CSR-sorted) ----------------
__global__ __launch_bounds__(256) void agg_kernel(
    const unsigned short* __restrict__ smsg, const unsigned short* __restrict__ vmsg,
    const int* __restrict__ offs,
    unsigned short* __restrict__ s_agg_bf, float* __restrict__ v_agg)
{
    int wave = blockIdx.x * 4 + (threadIdx.x >> 6);
    int lane = threadIdx.x & 63;
    if (wave >= N_NODES) return;
    int beg = offs[wave], end = offs[wave + 1];
    float a0 = 0.0f, a1 = 0.0f, va = 0.0f;
    const ushort2* sm2 = reinterpret_cast<const ushort2*>(smsg);
    for (int i = beg; i < end; i++) {
        ushort2 mm = sm2[(size_t)i * 64 + lane];
        a0 += bf2f(mm.x);
        a1 += bf2f(mm.y);
        if (lane < 9) va += bf2f(vmsg[(size_t)i * 12 + lane]);
    }
    ushort2 o; o.x = f2bf(a0); o.y = f2bf(a1);
    *reinterpret_cast<ushort2*>(s_agg_bf + (size_t)wave * SD + lane * 2) = o;
    if (lane < 9) v_agg[(size_t)wave * 9 + lane] = va;
}

// ---------------- MFMA node kernel ----------------
__global__ __launch_bounds__(256) void node_mfma(
    float* __restrict__ s, float* __restrict__ v, unsigned short* __restrict__ s_bf,
    const unsigned short* __restrict__ s_agg_bf, const float* __restrict__ v_agg,
    const float* __restrict__ inv_cnt,
    const unsigned short* __restrict__ Wn_l,
    const float* __restrict__ bn1, const float* __restrict__ bn2)
{
    __shared__ __align__(16) unsigned short Hb[4][16 * 72];   // 9216 B

    const int tid  = threadIdx.x;
    const int wl   = tid >> 6;
    const int lane = tid & 63;
    const int lo   = lane & 15;
    const int q    = lane >> 4;
    const int nb   = blockIdx.x * 64 + wl * 16;   // wave's first node

    int na = nb + lo; if (na > N_NODES - 1) na = N_NODES - 1;
    const unsigned short* rs = s_bf     + (size_t)na * SD;
    const unsigned short* ra = s_agg_bf + (size_t)na * SD;

    // ---- L1: [s | s_agg] @ Wn1 + bn1 ----
    f32x4 acc1[4];
    #pragma unroll
    for (int t = 0; t < 4; t++) {
        float bb = bn1[t * 16 + lo];
        #pragma unroll
        for (int rr = 0; rr < 4; rr++) acc1[t][rr] = bb;
    }
    #pragma unroll
    for (int ks = 0; ks < 4; ks++) {
        short8 a = *reinterpret_cast<const short8*>(rs + ks * 32 + q * 8);
        #pragma unroll
        for (int t = 0; t < 4; t++) {
            short8 b = *reinterpret_cast<const short8*>(Wn_l + (t * 16 + lo) * 256 + ks * 32 + q * 8);
            acc1[t] = __builtin_amdgcn_mfma_f32_16x16x32_bf16(a, b, acc1[t], 0, 0, 0);
        }
    }
    #pragma unroll
    for (int ks = 0; ks < 4; ks++) {
        short8 a = *reinterpret_cast<const short8*>(ra + ks * 32 + q * 8);
        #pragma unroll
        for (int t = 0; t < 4; t++) {
            short8 b = *reinterpret_cast<const short8*>(Wn_l + (t * 16 + lo) * 256 + 128 + ks * 32 + q * 8);
            acc1[t] = __builtin_amdgcn_mfma_f32_16x16x32_bf16(a, b, acc1[t], 0, 0, 0);
        }
    }
    #pragma unroll
    for (int t = 0; t < 4; t++)
        #pragma unroll
        for (int rr = 0; rr < 4; rr++)
            Hb[wl][(4 * q + rr) * 72 + t * 16 + lo] = f2bf(silu_f(acc1[t][rr]));
    __syncthreads();

    // ---- L2: u @ Wn2 + bn2, K=64, 128 cols ----
    const unsigned short* w2g = Wn_l + WN1T_SH;
    f32x4 acc2[8];
    #pragma unroll
    for (int t = 0; t < 8; t++) {
        float bb = bn2[t * 16 + lo];
        #pragma unroll
        for (int rr = 0; rr < 4; rr++) acc2[t][rr] = bb;
    }
    #pragma unroll
    for (int ks = 0; ks < 2; ks++) {
        short8 a = *reinterpret_cast<const short8*>(&Hb[wl][lo * 72 + ks * 32 + q * 8]);
        #pragma unroll
        for (int t = 0; t < 8; t++) {
            short8 b = *reinterpret_cast<const short8*>(w2g + (t * 16 + lo) * 64 + ks * 32 + q * 8);
            acc2[t] = __builtin_amdgcn_mfma_f32_16x16x32_bf16(a, b, acc2[t], 0, 0, 0);
        }
    }

    // ---- residual add + store fp32 s and bf16 s_bf ----
    #pragma unroll
    for (int t = 0; t < 8; t++) {
        int col = t * 16 + lo;
        #pragma unroll
        for (int rr = 0; rr < 4; rr++) {
            int node = nb + 4 * q + rr;
            if (node < N_NODES) {
                size_t idx = (size_t)node * SD + col;
                float ns = s[idx] + acc2[t][rr];
                s[idx] = ns;
                s_bf[idx] = f2bf(ns);
            }
        }
    }

    // ---- v update: one node per lane (lanes 0..15) ----
    if (lane < 16) {
        int node = nb + lane;
        if (node < N_NODES) {
            float ic = inv_cnt[node];
            #pragma unroll
            for (int t = 0; t < VD * 3; t++)
                v[(size_t)node * 9 + t] += v_agg[(size_t)node * 9 + t] * ic;
        }
    }
}

// ---------------- launch ----------------
extern "C" void kernel_launch(void* const* d_in, const int* in_sizes, int n_in,
                              void* d_out, int out_size, void* d_ws, size_t ws_size,
                              hipStream_t stream)
{
    (void)in_sizes; (void)n_in; (void)out_size; (void)ws_size;
    const float* s_in = (const float*)d_in[0];
    const float* v_in = (const float*)d_in[1];
    const int*   ei   = (const int*)d_in[2];
    const float* d_e  = (const float*)d_in[3];
    const float* r_e  = (const float*)d_in[4];
    const float* W1   = (const float*)d_in[5];
    const float* b1   = (const float*)d_in[6];
    const float* W2   = (const float*)d_in[7];
    const float* b2   = (const float*)d_in[8];
    const float* W3   = (const float*)d_in[9];
    const float* b3   = (const float*)d_in[10];
    const float* Wn1  = (const float*)d_in[11];
    const float* bn1  = (const float*)d_in[12];
    const float* Wn2  = (const float*)d_in[13];
    const float* bn2  = (const float*)d_in[14];

    float* s = (float*)d_out;                 // N*SD, updated in place
    float* v = s + (size_t)N_NODES * SD;      // N*VD*3

    // ---- workspace layout ----
    float* ws      = (float*)d_ws;
    float* v_agg   = ws;                                        // N*9
    float* cntinv  = v_agg + (size_t)N_NODES * 9;               // N
    float* Cbuf    = cntinv + N_NODES;                          // E
    int*   cnti    = (int*)(Cbuf + N_EDGES);                    // N
    int*   offs    = cnti + N_NODES;                            // N+1
    int*   cursor  = offs + N_NODES + 1;                        // N
    int*   eids    = cursor + N_NODES;                          // E
    int*   bsum    = eids + N_EDGES;                            // 64
    int*   dst_s   = bsum + 64;                                 // E
    int*   src_s   = dst_s + N_EDGES;                           // E
    float* d_s     = (float*)(src_s + N_EDGES);                 // E
    float* C_s     = d_s + N_EDGES;                             // E
    float* r_s     = C_s + N_EDGES;                             // 3E
    uintptr_t up   = (uintptr_t)(r_s + (size_t)3 * N_EDGES);
    up = (up + 15) & ~(uintptr_t)15;
    unsigned short* s_bf     = (unsigned short*)up;             // N*SD
    unsigned short* s_agg_bf = s_bf + (size_t)N_NODES * SD;     // N*SD
    unsigned short* Wpk      = s_agg_bf + (size_t)N_NODES * SD; // DEPTH*WPK_SH
    unsigned short* Wnpk     = Wpk + (size_t)DEPTH * WPK_SH;    // DEPTH*WN_SH
    unsigned short* smsg     = Wnpk + (size_t)DEPTH * WN_SH;    // E*128
    unsigned short* vmsg     = smsg + (size_t)N_EDGES * SD;     // E*12

    hipMemsetAsync(cnti, 0, sizeof(int) * (size_t)N_NODES, stream);
    hipMemsetAsync(cursor, 0, sizeof(int) * (size_t)N_NODES, stream);

    cast_s_kernel<<<(N_NODES * SD + 255) / 256, 256, 0, stream>>>(s_in, s, s_bf, N_NODES * SD);
    copy_kernel<<<(N_NODES * VD * 3 + 255) / 256, 256, 0, stream>>>(v_in, v, N_NODES * VD * 3);
    prep_edges<<<(N_EDGES + 255) / 256, 256, 0, stream>>>(ei, d_e, Cbuf, cnti);
    inv_cnt_kernel<<<(N_NODES + 255) / 256, 256, 0, stream>>>(cnti, cntinv);

    const int NB = (N_NODES + 1023) / 1024;   // 49
    scan_block<<<NB, 1024, 0, stream>>>(cnti, offs, bsum);
    scan_partials<<<1, 64, 0, stream>>>(bsum, NB, offs + N_NODES);
    scan_apply<<<NB, 1024, 0, stream>>>(offs, bsum);
    build_perm<<<(N_EDGES + 255) / 256, 256, 0, stream>>>(ei, offs, cursor, eids);
    permute_edges<<<(N_EDGES + 255) / 256, 256, 0, stream>>>(
        ei, d_e, Cbuf, r_e, eids, dst_s, src_s, d_s, C_s, r_s);

    prep_weights<<<(DEPTH * WPK_SH + 255) / 256, 256, 0, stream>>>(W1, W2, W3, Wpk);
    prep_node_weights<<<(DEPTH * WN_SH + 255) / 256, 256, 0, stream>>>(Wn1, Wn2, Wnpk);

    for (int l = 0; l < DEPTH; l++) {
        edge_mfma<<<N_EDGES / 16, 64, 0, stream>>>(
            s_bf, v, dst_s, src_s, d_s, C_s, r_s,
            Wpk + (size_t)l * WPK_SH,
            W1 + ((size_t)l * 257 + 256) * 64,
            b1 + (size_t)l * HID, b2 + (size_t)l * HID, b3 + (size_t)l * (SD + 2 * VD),
            smsg, vmsg);
        agg_kernel<<<(N_NODES + 3) / 4, 256, 0, stream>>>(
            smsg, vmsg, offs, s_agg_bf, v_agg);
        node_mfma<<<(N_NODES + 63) / 64, 256, 0, stream>>>(
            s, v, s_bf, s_agg_bf, v_agg, cntinv,
            Wnpk + (size_t)l * WN_SH,
            bn1 + (size_t)l * HID, bn2 + (size_t)l * SD);
    }
}

// Round 6
// 954.910 us; speedup vs baseline: 16.5634x; 1.2566x over previous
//
#include <hip/hip_runtime.h>
#include <hip/hip_bf16.h>
#include <math.h>

#define N_NODES 50000
#define N_EDGES 500000
#define SD 128
#define VD 3
#define HID 64
#define DEPTH 4

// edge weights per layer, MFMA-fragment order: frag = [f][lane(64)][8 shorts]
// W1F: 32 frags (f = ks*4+t, ks 0..7 over K=256, t 0..3 over N=64)
// W2F:  8 frags (f = ks*4+t, ks 0..1)
// W3F: 18 frags (f = ks*9+t, ks 0..1, t 0..8 over N=144 padded)
#define NF1 32
#define NF2 8
#define NF3 18
#define W1F_SH (NF1 * 512)
#define W2F_SH (NF2 * 512)
#define W3F_SH (NF3 * 512)
#define WPK_SH (W1F_SH + W2F_SH + W3F_SH)   // 29696 shorts per layer

// node weights per layer: Wn1T (64 x 256) + Wn2T (128 x 64), row-major transposed
#define WN1T_SH (64 * 256)
#define WN2T_SH (128 * 64)
#define WN_SH (WN1T_SH + WN2T_SH)

#define EDGE_GRID 512
#define NTILES (N_EDGES / 16)               // 31250
#define EDGE_ITERS ((NTILES + EDGE_GRID * 4 - 1) / (EDGE_GRID * 4))   // 16

typedef __attribute__((ext_vector_type(8))) short short8;
typedef __attribute__((ext_vector_type(4))) float f32x4;

__device__ __forceinline__ float silu_f(float x) {
    return x / (1.0f + __expf(-x));
}

__device__ __forceinline__ unsigned short f2bf(float x) {
    __hip_bfloat16 h = __float2bfloat16(x);
    return *reinterpret_cast<unsigned short*>(&h);
}

__device__ __forceinline__ float bf2f(unsigned short u) {
    union { unsigned int i; float f; } c; c.i = ((unsigned int)u) << 16;
    return c.f;
}

// ---------------- setup kernels ----------------

__global__ void cast_s_kernel(const float* __restrict__ in, float* __restrict__ out,
                              unsigned short* __restrict__ out_bf, int n) {
    int i = blockIdx.x * blockDim.x + threadIdx.x;
    if (i < n) { float x = in[i]; out[i] = x; out_bf[i] = f2bf(x); }
}

__global__ void copy_kernel(const float* __restrict__ in, float* __restrict__ out, int n) {
    int i = blockIdx.x * blockDim.x + threadIdx.x;
    if (i < n) out[i] = in[i];
}

__global__ void prep_edges(const int* __restrict__ ei, const float* __restrict__ d,
                           float* __restrict__ C, int* __restrict__ cnti) {
    int e = blockIdx.x * blockDim.x + threadIdx.x;
    if (e >= N_EDGES) return;
    float de = d[e];
    float c = 0.5f * (cosf(3.14159265358979323846f * de * (1.0f / 5.0f)) + 1.0f);
    C[e] = (de < 5.0f) ? c : 0.0f;
    atomicAdd(&cnti[ei[e]], 1);
}

__global__ void inv_cnt_kernel(const int* __restrict__ cnti, float* __restrict__ inv_cnt) {
    int i = blockIdx.x * blockDim.x + threadIdx.x;
    if (i < N_NODES) inv_cnt[i] = 1.0f / fmaxf((float)cnti[i], 1.0f);
}

// multi-block scan: phase 1 — per-block exclusive scan + block sums
__global__ __launch_bounds__(1024) void scan_block(const int* __restrict__ cnti,
                                                   int* __restrict__ offs,
                                                   int* __restrict__ bsum) {
    __shared__ int sh[1024];
    int tid = threadIdx.x;
    int idx = blockIdx.x * 1024 + tid;
    int x = (idx < N_NODES) ? cnti[idx] : 0;
    sh[tid] = x;
    __syncthreads();
    for (int off = 1; off < 1024; off <<= 1) {
        int y = (tid >= off) ? sh[tid - off] : 0;
        __syncthreads();
        sh[tid] += y;
        __syncthreads();
    }
    if (idx < N_NODES) offs[idx] = sh[tid] - x;   // exclusive, block-local
    if (tid == 1023) bsum[blockIdx.x] = sh[1023];
}

__global__ void scan_partials(int* __restrict__ bsum, int nb, int* __restrict__ offs_total) {
    if (threadIdx.x == 0 && blockIdx.x == 0) {
        int acc = 0;
        for (int i = 0; i < nb; i++) { int t = bsum[i]; bsum[i] = acc; acc += t; }
        offs_total[0] = acc;
    }
}

__global__ __launch_bounds__(1024) void scan_apply(int* __restrict__ offs,
                                                   const int* __restrict__ bsum) {
    int idx = blockIdx.x * 1024 + threadIdx.x;
    if (idx < N_NODES) offs[idx] += bsum[blockIdx.x];
}

__global__ void build_perm(const int* __restrict__ ei, const int* __restrict__ offs,
                           int* __restrict__ cursor, int* __restrict__ eids) {
    int e = blockIdx.x * blockDim.x + threadIdx.x;
    if (e >= N_EDGES) return;
    int dst = ei[e];
    int p = offs[dst] + atomicAdd(&cursor[dst], 1);
    eids[p] = e;
}

// permute per-edge data into CSR (dst-sorted) order
__global__ void permute_edges(const int* __restrict__ ei, const float* __restrict__ d,
                              const float* __restrict__ C, const float* __restrict__ r,
                              const int* __restrict__ eids,
                              int* __restrict__ dst_s, int* __restrict__ src_s,
                              float* __restrict__ d_s, float* __restrict__ C_s,
                              float* __restrict__ r_s) {
    int p = blockIdx.x * blockDim.x + threadIdx.x;
    if (p >= N_EDGES) return;
    int e = eids[p];
    dst_s[p] = ei[e];
    src_s[p] = ei[N_EDGES + e];
    d_s[p] = d[e];
    C_s[p] = C[e];
    r_s[3 * (size_t)p + 0] = r[3 * (size_t)e + 0];
    r_s[3 * (size_t)p + 1] = r[3 * (size_t)e + 1];
    r_s[3 * (size_t)p + 2] = r[3 * (size_t)e + 2];
}

// pack edge-MLP weights into bf16 MFMA-fragment order (see defines above)
__global__ void prep_weights(const float* __restrict__ W1, const float* __restrict__ W2,
                             const float* __restrict__ W3, unsigned short* __restrict__ Wpk) {
    int idx = blockIdx.x * blockDim.x + threadIdx.x;
    if (idx >= DEPTH * WPK_SH) return;
    int l = idx / WPK_SH;
    int j = idx - l * WPK_SH;
    float val = 0.0f;
    if (j < W1F_SH) {
        int f = j >> 9, rrr = j & 511;
        int lane = rrr >> 3, jj = rrr & 7;
        int q = lane >> 4, lo = lane & 15;
        int ks = f >> 2, t = f & 3;
        int k = ks * 32 + q * 8 + jj;        // 0..255
        int n = t * 16 + lo;                 // 0..63
        val = W1[((size_t)l * 257 + k) * 64 + n];
    } else if (j < W1F_SH + W2F_SH) {
        int jj2 = j - W1F_SH;
        int f = jj2 >> 9, rrr = jj2 & 511;
        int lane = rrr >> 3, jj = rrr & 7;
        int q = lane >> 4, lo = lane & 15;
        int ks = f >> 2, t = f & 3;
        int k = ks * 32 + q * 8 + jj;        // 0..63
        int n = t * 16 + lo;
        val = W2[((size_t)l * 64 + k) * 64 + n];
    } else {
        int jj3 = j - W1F_SH - W2F_SH;
        int f = jj3 >> 9, rrr = jj3 & 511;
        int lane = rrr >> 3, jj = rrr & 7;
        int q = lane >> 4, lo = lane & 15;
        int ks = f / 9, t = f - ks * 9;
        int k = ks * 32 + q * 8 + jj;        // 0..63
        int n = t * 16 + lo;                 // 0..143 (valid < 134)
        val = (n < 134) ? W3[((size_t)l * 64 + k) * 134 + n] : 0.0f;
    }
    Wpk[idx] = f2bf(val);
}

// pack transposed bf16 node-MLP weights: Wn1T[n][k] (64x256), Wn2T[n][k] (128x64)
__global__ void prep_node_weights(const float* __restrict__ Wn1, const float* __restrict__ Wn2,
                                  unsigned short* __restrict__ Wnpk) {
    int idx = blockIdx.x * blockDim.x + threadIdx.x;
    if (idx >= DEPTH * WN_SH) return;
    int l = idx / WN_SH;
    int j = idx - l * WN_SH;
    float val;
    if (j < WN1T_SH) {
        int n = j / 256, k = j - n * 256;
        val = Wn1[((size_t)l * 256 + k) * 64 + n];
    } else {
        int jj = j - WN1T_SH;
        int n = jj / 64, k = jj - n * 64;
        val = Wn2[((size_t)l * 64 + k) * 128 + n];
    }
    Wnpk[idx] = f2bf(val);
}

// ---------------- persistent MFMA edge kernel ----------------
// 512 blocks x 4 waves; W1F/W3F staged in LDS once per block (fragment order,
// conflict-free ds_read_b128); W2F from global (L1-hot). Each wave processes
// EDGE_ITERS tiles of 16 edges with depth-1 software pipelining of the
// A-fragment / tail gathers.
__global__ __launch_bounds__(256, 2) void edge_mfma(
    const unsigned short* __restrict__ s_bf, const float* __restrict__ v,
    const int* __restrict__ dst_s, const int* __restrict__ src_s,
    const float* __restrict__ d_s, const float* __restrict__ C_s,
    const float* __restrict__ r_s,
    const unsigned short* __restrict__ Wpk_l,
    const float* __restrict__ W1r,              // fp32 W1 row 256 (the d feature)
    const float* __restrict__ b1, const float* __restrict__ b2,
    const float* __restrict__ b3,
    unsigned short* __restrict__ smsg, unsigned short* __restrict__ vmsg)
{
    __shared__ __align__(16) unsigned short w1f[W1F_SH];      // 32768 B
    __shared__ __align__(16) unsigned short w3f[W3F_SH];      // 18432 B
    __shared__ __align__(16) unsigned short Hb[4][16 * 72];   //  9216 B
    __shared__ float gb[4][16][6];                            //  1536 B

    const int tid  = threadIdx.x;
    const int wl   = tid >> 6;
    const int lane = tid & 63;
    const int lo   = lane & 15;
    const int q    = lane >> 4;

    // ---- stage W1F + W3F into LDS (fragment order = straight 16B copies) ----
    {
        const short8* g1 = reinterpret_cast<const short8*>(Wpk_l);
        const short8* g3 = reinterpret_cast<const short8*>(Wpk_l + W1F_SH + W2F_SH);
        short8* l1 = reinterpret_cast<short8*>(w1f);
        short8* l3 = reinterpret_cast<short8*>(w3f);
        for (int i = tid; i < W1F_SH / 8; i += 256) l1[i] = g1[i];
        for (int i = tid; i < W3F_SH / 8; i += 256) l3[i] = g3[i];
    }
    __syncthreads();

    const unsigned short* w2g = Wpk_l + W1F_SH;

    // per-lane wave-uniform-ish scalars
    float bb1[4], wr1[4], bb2[4], bb3[9];
    #pragma unroll
    for (int t = 0; t < 4; t++) { bb1[t] = b1[t * 16 + lo]; wr1[t] = W1r[t * 16 + lo]; }
    #pragma unroll
    for (int t = 0; t < 4; t++) bb2[t] = b2[t * 16 + lo];
    #pragma unroll
    for (int t = 0; t < 9; t++) { int n = t * 16 + lo; bb3[t] = (n < 134) ? b3[n] : 0.0f; }

    // ---- pipeline state: current tile's loads ----
    int tile = blockIdx.x * 4 + wl;
    if (tile > NTILES - 1) tile = NTILES - 1;
    long eb = (long)tile * 16;
    int sn_t = 0;                 // tail src node (lane<16)
    short8 ad[4], asf[4];
    float4 dd4, ce4;
    float vsr[9], rv[3], cel_t = 0.0f;
    {
        int dn = dst_s[eb + lo];
        int sn = src_s[eb + lo];
        dd4 = *reinterpret_cast<const float4*>(d_s + eb + 4 * q);
        ce4 = *reinterpret_cast<const float4*>(C_s + eb + 4 * q);
        const unsigned short* rd = s_bf + (size_t)dn * SD;
        const unsigned short* rs = s_bf + (size_t)sn * SD;
        #pragma unroll
        for (int ks = 0; ks < 4; ks++) {
            ad[ks]  = *reinterpret_cast<const short8*>(rd + ks * 32 + q * 8);
            asf[ks] = *reinterpret_cast<const short8*>(rs + ks * 32 + q * 8);
        }
        if (lane < 16) {
            sn_t = sn;
            cel_t = C_s[eb + lane];
            #pragma unroll
            for (int t = 0; t < 9; t++) vsr[t] = v[(size_t)sn * 9 + t];
            #pragma unroll
            for (int t = 0; t < 3; t++) rv[t] = r_s[3 * eb + 3 * lane + t];
        }
    }

    for (int it = 0; it < EDGE_ITERS; it++) {
        // ---- phase A: issue next tile's index loads ----
        int tile_n = (it + 1) * (EDGE_GRID * 4) + blockIdx.x * 4 + wl;
        if (tile_n > NTILES - 1) tile_n = NTILES - 1;
        long ebn = (long)tile_n * 16;
        int dn_n = dst_s[ebn + lo];
        int sn_n = src_s[ebn + lo];
        float4 dd4_n = *reinterpret_cast<const float4*>(d_s + ebn + 4 * q);
        float4 ce4_n = *reinterpret_cast<const float4*>(C_s + ebn + 4 * q);
        float cel_n = 0.0f, rv_n[3];
        if (lane < 16) {
            cel_n = C_s[ebn + lane];
            #pragma unroll
            for (int t = 0; t < 3; t++) rv_n[t] = r_s[3 * ebn + 3 * lane + t];
        }

        // ---- L1: [s_dst | s_src | d] @ W1 + b1 (K=256) ----
        f32x4 acc1[4];
        #pragma unroll
        for (int t = 0; t < 4; t++) {
            float dd[4] = { dd4.x, dd4.y, dd4.z, dd4.w };
            #pragma unroll
            for (int rr = 0; rr < 4; rr++) acc1[t][rr] = bb1[t] + dd[rr] * wr1[t];
        }
        #pragma unroll
        for (int ks = 0; ks < 4; ks++) {
            #pragma unroll
            for (int t = 0; t < 4; t++) {
                short8 b = *reinterpret_cast<const short8*>(&w1f[((ks * 4 + t) * 64 + lane) * 8]);
                acc1[t] = __builtin_amdgcn_mfma_f32_16x16x32_bf16(ad[ks], b, acc1[t], 0, 0, 0);
            }
        }
        #pragma unroll
        for (int ks = 0; ks < 4; ks++) {
            #pragma unroll
            for (int t = 0; t < 4; t++) {
                short8 b = *reinterpret_cast<const short8*>(&w1f[(((ks + 4) * 4 + t) * 64 + lane) * 8]);
                acc1[t] = __builtin_amdgcn_mfma_f32_16x16x32_bf16(asf[ks], b, acc1[t], 0, 0, 0);
            }
        }
        #pragma unroll
        for (int t = 0; t < 4; t++)
            #pragma unroll
            for (int rr = 0; rr < 4; rr++)
                Hb[wl][(4 * q + rr) * 72 + t * 16 + lo] = f2bf(silu_f(acc1[t][rr]));
        __syncthreads();

        // ---- L2: H1 @ W2 + b2 (K=64), W2 frags from global (L1-hot) ----
        short8 a2[2];
        #pragma unroll
        for (int ks = 0; ks < 2; ks++)
            a2[ks] = *reinterpret_cast<const short8*>(&Hb[wl][lo * 72 + ks * 32 + q * 8]);
        f32x4 acc2[4];
        #pragma unroll
        for (int t = 0; t < 4; t++) {
            #pragma unroll
            for (int rr = 0; rr < 4; rr++) acc2[t][rr] = bb2[t];
        }
        #pragma unroll
        for (int ks = 0; ks < 2; ks++) {
            #pragma unroll
            for (int t = 0; t < 4; t++) {
                short8 b = *reinterpret_cast<const short8*>(w2g + ((ks * 4 + t) * 64 + lane) * 8);
                acc2[t] = __builtin_amdgcn_mfma_f32_16x16x32_bf16(a2[ks], b, acc2[t], 0, 0, 0);
            }
        }

        // ---- phase B: issue next tile's A-fragment + tail gathers ----
        short8 ad_n[4], as_n[4];
        {
            const unsigned short* rd = s_bf + (size_t)dn_n * SD;
            const unsigned short* rs = s_bf + (size_t)sn_n * SD;
            #pragma unroll
            for (int ks = 0; ks < 4; ks++) {
                ad_n[ks] = *reinterpret_cast<const short8*>(rd + ks * 32 + q * 8);
                as_n[ks] = *reinterpret_cast<const short8*>(rs + ks * 32 + q * 8);
            }
        }
        float vsr_n[9];
        if (lane < 16) {
            #pragma unroll
            for (int t = 0; t < 9; t++) vsr_n[t] = v[(size_t)sn_n * 9 + t];
        }

        __syncthreads();
        #pragma unroll
        for (int t = 0; t < 4; t++)
            #pragma unroll
            for (int rr = 0; rr < 4; rr++)
                Hb[wl][(4 * q + rr) * 72 + t * 16 + lo] = f2bf(silu_f(acc2[t][rr]));
        __syncthreads();

        // ---- L3: H2 @ W3 + b3 (K=64, 144 padded cols), W3 frags from LDS ----
        short8 a3[2];
        #pragma unroll
        for (int ks = 0; ks < 2; ks++)
            a3[ks] = *reinterpret_cast<const short8*>(&Hb[wl][lo * 72 + ks * 32 + q * 8]);
        f32x4 acc3[9];
        #pragma unroll
        for (int t = 0; t < 9; t++) {
            #pragma unroll
            for (int rr = 0; rr < 4; rr++) acc3[t][rr] = bb3[t];
        }
        #pragma unroll
        for (int ks = 0; ks < 2; ks++) {
            #pragma unroll
            for (int t = 0; t < 9; t++) {
                short8 b = *reinterpret_cast<const short8*>(&w3f[((ks * 9 + t) * 64 + lane) * 8]);
                acc3[t] = __builtin_amdgcn_mfma_f32_16x16x32_bf16(a3[ks], b, acc3[t], 0, 0, 0);
            }
        }

        // store smsg (cols 0..127), scaled by C
        float ce[4] = { ce4.x, ce4.y, ce4.z, ce4.w };
        #pragma unroll
        for (int t = 0; t < 8; t++) {
            int colc = t * 16 + lo;
            #pragma unroll
            for (int rr = 0; rr < 4; rr++) {
                long erow = eb + 4 * q + rr;
                smsg[erow * SD + colc] = f2bf(acc3[t][rr] * ce[rr]);
            }
        }
        // stash gv/gr (cols 128..133)
        if (lo < 6) {
            #pragma unroll
            for (int rr = 0; rr < 4; rr++) gb[wl][4 * q + rr][lo] = acc3[8][rr];
        }
        __syncthreads();

        // per-edge tail: vm = (v[src]*gv + r*gr) * C -> bf16 vmsg
        if (lane < 16) {
            long e = eb + lane;
            #pragma unroll
            for (int vi = 0; vi < VD; vi++) {
                float gv = gb[wl][lane][vi], gr = gb[wl][lane][VD + vi];
                vmsg[e * 12 + vi * 3 + 0] = f2bf((vsr[vi * 3 + 0] * gv + rv[0] * gr) * cel_t);
                vmsg[e * 12 + vi * 3 + 1] = f2bf((vsr[vi * 3 + 1] * gv + rv[1] * gr) * cel_t);
                vmsg[e * 12 + vi * 3 + 2] = f2bf((vsr[vi * 3 + 2] * gv + rv[2] * gr) * cel_t);
            }
        }

        // ---- rotate pipeline state ----
        eb = ebn;
        dd4 = dd4_n; ce4 = ce4_n;
        cel_t = cel_n; sn_t = sn_n;
        #pragma unroll
        for (int ks = 0; ks < 4; ks++) { ad[ks] = ad_n[ks]; asf[ks] = as_n[ks]; }
        #pragma unroll
        for (int t = 0; t < 9; t++) vsr[t] = vsr_n[t];
        #pragma unroll
        for (int t = 0; t < 3; t++) rv[t] = rv_n[t];
    }
}

// ---------------- aggregation kernel (streaming: smsg is CSR-sorted) ----------------
__global__ __launch_bounds__(256) void agg_kernel(
    const unsigned short* __restrict__ smsg, const unsigned short* __restrict__ vmsg,
    const int* __restrict__ offs,
    unsigned short* __restrict__ s_agg_bf, float* __restrict__ v_agg)
{
    int wave = blockIdx.x * 4 + (threadIdx.x >> 6);
    int lane = threadIdx.x & 63;
    if (wave >= N_NODES) return;
    int beg = offs[wave], end = offs[wave + 1];
    float a0 = 0.0f, a1 = 0.0f, va = 0.0f;
    const ushort2* sm2 = reinterpret_cast<const ushort2*>(smsg);
    for (int i = beg; i < end; i++) {
        ushort2 mm = sm2[(size_t)i * 64 + lane];
        a0 += bf2f(mm.x);
        a1 += bf2f(mm.y);
        if (lane < 9) va += bf2f(vmsg[(size_t)i * 12 + lane]);
    }
    ushort2 o; o.x = f2bf(a0); o.y = f2bf(a1);
    *reinterpret_cast<ushort2*>(s_agg_bf + (size_t)wave * SD + lane * 2) = o;
    if (lane < 9) v_agg[(size_t)wave * 9 + lane] = va;
}

// ---------------- MFMA node kernel ----------------
__global__ __launch_bounds__(256) void node_mfma(
    float* __restrict__ s, float* __restrict__ v, unsigned short* __restrict__ s_bf,
    const unsigned short* __restrict__ s_agg_bf, const float* __restrict__ v_agg,
    const float* __restrict__ inv_cnt,
    const unsigned short* __restrict__ Wn_l,
    const float* __restrict__ bn1, const float* __restrict__ bn2)
{
    __shared__ __align__(16) unsigned short Hb[4][16 * 72];   // 9216 B

    const int tid  = threadIdx.x;
    const int wl   = tid >> 6;
    const int lane = tid & 63;
    const int lo   = lane & 15;
    const int q    = lane >> 4;
    const int nb   = blockIdx.x * 64 + wl * 16;   // wave's first node

    int na = nb + lo; if (na > N_NODES - 1) na = N_NODES - 1;
    const unsigned short* rs = s_bf     + (size_t)na * SD;
    const unsigned short* ra = s_agg_bf + (size_t)na * SD;

    // ---- L1: [s | s_agg] @ Wn1 + bn1 ----
    f32x4 acc1[4];
    #pragma unroll
    for (int t = 0; t < 4; t++) {
        float bb = bn1[t * 16 + lo];
        #pragma unroll
        for (int rr = 0; rr < 4; rr++) acc1[t][rr] = bb;
    }
    #pragma unroll
    for (int ks = 0; ks < 4; ks++) {
        short8 a = *reinterpret_cast<const short8*>(rs + ks * 32 + q * 8);
        #pragma unroll
        for (int t = 0; t < 4; t++) {
            short8 b = *reinterpret_cast<const short8*>(Wn_l + (t * 16 + lo) * 256 + ks * 32 + q * 8);
            acc1[t] = __builtin_amdgcn_mfma_f32_16x16x32_bf16(a, b, acc1[t], 0, 0, 0);
        }
    }
    #pragma unroll
    for (int ks = 0; ks < 4; ks++) {
        short8 a = *reinterpret_cast<const short8*>(ra + ks * 32 + q * 8);
        #pragma unroll
        for (int t = 0; t < 4; t++) {
            short8 b = *reinterpret_cast<const short8*>(Wn_l + (t * 16 + lo) * 256 + 128 + ks * 32 + q * 8);
            acc1[t] = __builtin_amdgcn_mfma_f32_16x16x32_bf16(a, b, acc1[t], 0, 0, 0);
        }
    }
    #pragma unroll
    for (int t = 0; t < 4; t++)
        #pragma unroll
        for (int rr = 0; rr < 4; rr++)
            Hb[wl][(4 * q + rr) * 72 + t * 16 + lo] = f2bf(silu_f(acc1[t][rr]));
    __syncthreads();

    // ---- L2: u @ Wn2 + bn2, K=64, 128 cols ----
    const unsigned short* w2g = Wn_l + WN1T_SH;
    f32x4 acc2[8];
    #pragma unroll
    for (int t = 0; t < 8; t++) {
        float bb = bn2[t * 16 + lo];
        #pragma unroll
        for (int rr = 0; rr < 4; rr++) acc2[t][rr] = bb;
    }
    #pragma unroll
    for (int ks = 0; ks < 2; ks++) {
        short8 a = *reinterpret_cast<const short8*>(&Hb[wl][lo * 72 + ks * 32 + q * 8]);
        #pragma unroll
        for (int t = 0; t < 8; t++) {
            short8 b = *reinterpret_cast<const short8*>(w2g + (t * 16 + lo) * 64 + ks * 32 + q * 8);
            acc2[t] = __builtin_amdgcn_mfma_f32_16x16x32_bf16(a, b, acc2[t], 0, 0, 0);
        }
    }

    // ---- residual add + store fp32 s and bf16 s_bf ----
    #pragma unroll
    for (int t = 0; t < 8; t++) {
        int col = t * 16 + lo;
        #pragma unroll
        for (int rr = 0; rr < 4; rr++) {
            int node = nb + 4 * q + rr;
            if (node < N_NODES) {
                size_t idx = (size_t)node * SD + col;
                float ns = s[idx] + acc2[t][rr];
                s[idx] = ns;
                s_bf[idx] = f2bf(ns);
            }
        }
    }

    // ---- v update: one node per lane (lanes 0..15) ----
    if (lane < 16) {
        int node = nb + lane;
        if (node < N_NODES) {
            float ic = inv_cnt[node];
            #pragma unroll
            for (int t = 0; t < VD * 3; t++)
                v[(size_t)node * 9 + t] += v_agg[(size_t)node * 9 + t] * ic;
        }
    }
}

// ---------------- launch ----------------
extern "C" void kernel_launch(void* const* d_in, const int* in_sizes, int n_in,
                              void* d_out, int out_size, void* d_ws, size_t ws_size,
                              hipStream_t stream)
{
    (void)in_sizes; (void)n_in; (void)out_size; (void)ws_size;
    const float* s_in = (const float*)d_in[0];
    const float* v_in = (const float*)d_in[1];
    const int*   ei   = (const int*)d_in[2];
    const float* d_e  = (const float*)d_in[3];
    const float* r_e  = (const float*)d_in[4];
    const float* W1   = (const float*)d_in[5];
    const float* b1   = (const float*)d_in[6];
    const float* W2   = (const float*)d_in[7];
    const float* b2   = (const float*)d_in[8];
    const float* W3   = (const float*)d_in[9];
    const float* b3   = (const float*)d_in[10];
    const float* Wn1  = (const float*)d_in[11];
    const float* bn1  = (const float*)d_in[12];
    const float* Wn2  = (const float*)d_in[13];
    const float* bn2  = (const float*)d_in[14];

    float* s = (float*)d_out;                 // N*SD, updated in place
    float* v = s + (size_t)N_NODES * SD;      // N*VD*3

    // ---- workspace layout ----
    float* ws      = (float*)d_ws;
    float* v_agg   = ws;                                        // N*9
    float* cntinv  = v_agg + (size_t)N_NODES * 9;               // N
    float* Cbuf    = cntinv + N_NODES;                          // E
    int*   cnti    = (int*)(Cbuf + N_EDGES);                    // N
    int*   offs    = cnti + N_NODES;                            // N+1
    int*   cursor  = offs + N_NODES + 1;                        // N
    int*   eids    = cursor + N_NODES;                          // E
    int*   bsum    = eids + N_EDGES;                            // 64
    int*   dst_s   = bsum + 64;                                 // E
    int*   src_s   = dst_s + N_EDGES;                           // E
    float* d_s     = (float*)(src_s + N_EDGES);                 // E
    float* C_s     = d_s + N_EDGES;                             // E
    float* r_s     = C_s + N_EDGES;                             // 3E
    uintptr_t up   = (uintptr_t)(r_s + (size_t)3 * N_EDGES);
    up = (up + 15) & ~(uintptr_t)15;
    unsigned short* s_bf     = (unsigned short*)up;             // N*SD
    unsigned short* s_agg_bf = s_bf + (size_t)N_NODES * SD;     // N*SD
    unsigned short* Wpk      = s_agg_bf + (size_t)N_NODES * SD; // DEPTH*WPK_SH
    unsigned short* Wnpk     = Wpk + (size_t)DEPTH * WPK_SH;    // DEPTH*WN_SH
    unsigned short* smsg     = Wnpk + (size_t)DEPTH * WN_SH;    // E*128
    unsigned short* vmsg     = smsg + (size_t)N_EDGES * SD;     // E*12

    hipMemsetAsync(cnti, 0, sizeof(int) * (size_t)N_NODES, stream);
    hipMemsetAsync(cursor, 0, sizeof(int) * (size_t)N_NODES, stream);

    cast_s_kernel<<<(N_NODES * SD + 255) / 256, 256, 0, stream>>>(s_in, s, s_bf, N_NODES * SD);
    copy_kernel<<<(N_NODES * VD * 3 + 255) / 256, 256, 0, stream>>>(v_in, v, N_NODES * VD * 3);
    prep_edges<<<(N_EDGES + 255) / 256, 256, 0, stream>>>(ei, d_e, Cbuf, cnti);
    inv_cnt_kernel<<<(N_NODES + 255) / 256, 256, 0, stream>>>(cnti, cntinv);

    const int NB = (N_NODES + 1023) / 1024;   // 49
    scan_block<<<NB, 1024, 0, stream>>>(cnti, offs, bsum);
    scan_partials<<<1, 64, 0, stream>>>(bsum, NB, offs + N_NODES);
    scan_apply<<<NB, 1024, 0, stream>>>(offs, bsum);
    build_perm<<<(N_EDGES + 255) / 256, 256, 0, stream>>>(ei, offs, cursor, eids);
    permute_edges<<<(N_EDGES + 255) / 256, 256, 0, stream>>>(
        ei, d_e, Cbuf, r_e, eids, dst_s, src_s, d_s, C_s, r_s);

    prep_weights<<<(DEPTH * WPK_SH + 255) / 256, 256, 0, stream>>>(W1, W2, W3, Wpk);
    prep_node_weights<<<(DEPTH * WN_SH + 255) / 256, 256, 0, stream>>>(Wn1, Wn2, Wnpk);

    for (int l = 0; l < DEPTH; l++) {
        edge_mfma<<<EDGE_GRID, 256, 0, stream>>>(
            s_bf, v, dst_s, src_s, d_s, C_s, r_s,
            Wpk + (size_t)l * WPK_SH,
            W1 + ((size_t)l * 257 + 256) * 64,
            b1 + (size_t)l * HID, b2 + (size_t)l * HID, b3 + (size_t)l * (SD + 2 * VD),
            smsg, vmsg);
        agg_kernel<<<(N_NODES + 3) / 4, 256, 0, stream>>>(
            smsg, vmsg, offs, s_agg_bf, v_agg);
        node_mfma<<<(N_NODES + 63) / 64, 256, 0, stream>>>(
            s, v, s_bf, s_agg_bf, v_agg, cntinv,
            Wnpk + (size_t)l * WN_SH,
            bn1 + (size_t)l * HID, bn2 + (size_t)l * SD);
    }
}